// Round 8
// baseline (155.585 us; speedup 1.0000x reference)
//
#include <hip/hip_runtime.h>
#include <math.h>

#define G    64
#define NPG  2048
#define EPG  (NPG * 8)          // 16384 edges per graph
#define KSEL 410
#define NH   3
#define NC   20
#define HC   60
#define FCAP 24
#define KPAD 512
#define RP   12                 // x1 row: x1[0..9], dinv@10, hs@11 (48 B)

// ---- workspace layout (bytes) ----
#define WS_X1G  0               // 64*2048*12*4 = 6291456
#define WS_KEYS 6291456         // 64*2048*4   = 524288
#define WS_PERM 6815744         // 64*512*2    = 65536 (stride 512 entries/graph)
#define WS_NEWL 6881280         // 64*2048*2   = 262144   (total 7143424)

// ---- kAB arena ----
#define A_H1P  0                // 98304  h1p 2048x12f
#define A_CSR  98304            // 32768  csr u16
#define A_HIST 131072           // 8192   hist[A] / pr[B..C]
#define A_RS   139264           // 8192   rs int
#define A_WSUM 147456           // 64
#define A_SZ   147520

// ---- k_sel arena ----
#define S_SK   0                // 8192
#define S_HIST 8192             // 8192
#define S_NEWL 16384            // 4096
#define S_PERM 20480            // 1024
#define S_WSUM 21504            // 64
#define S_FLAG 21568            // 16
#define S_SZ   21584

// ---- k_efgh arena ----
#define E_XP    0               // 16400  xp 410x10f
#define E_FADJ  16400           // 19680  fadj 410x24 u16
#define E_FCNT  36080           // 1648
#define E_HF    37728           // 98400  hf 410x60f [F..]; early aliases below die before F
#define E_NEWL  37728           // 4096   staged newL [..E1]
#define E_PERM  41824           // 1024   staged perm [..E2]
#define E_ALS   136128          // 4920
#define E_ALD   141048          // 4920
#define E_WRED  145968          // 1920
#define E_GOUT  147888          // 240
#define E_HID   148128          // 120
#define E_SZ    148248

__device__ inline float leaky(float x) { return x >= 0.f ? x : 0.2f * x; }

__device__ inline int wave_incl_scan(int v) {
    int lane = threadIdx.x & 63;
#pragma unroll
    for (int d = 1; d < 64; d <<= 1) {
        int t = __shfl_up(v, d, 64);
        if (lane >= d) v += t;
    }
    return v;
}

// ================= kAB: phases A+B+C (CSR, GCN10, scorer keys) =================
__global__ __launch_bounds__(1024) void k_ab(
    const float* __restrict__ x, const int* __restrict__ src, const int* __restrict__ dst,
    const float* __restrict__ W1, const float* __restrict__ b1,
    const float* __restrict__ Ws, const float* __restrict__ bs,
    float* __restrict__ x1g, unsigned* __restrict__ keysG)
{
    __shared__ __align__(16) char arena[A_SZ];
    float*          h1p   = (float*)(arena + A_H1P);
    unsigned short* csrL  = (unsigned short*)(arena + A_CSR);
    int*            hist  = (int*)(arena + A_HIST);
    float*          prB   = (float*)(arena + A_HIST);
    int*            rsL   = (int*)(arena + A_RS);
    int*            wsumL = (int*)(arena + A_WSUM);

    int g = blockIdx.x, tid = threadIdx.x, wid = tid >> 6;
    int nbase = g * NPG, ebase = g * EPG;

    // ---- Phase A
    for (int i = tid; i < NPG; i += 1024) hist[i] = 0;
    for (int i = tid; i < NPG; i += 1024) {
        float xi[5];
#pragma unroll
        for (int k = 0; k < 5; k++) xi[k] = x[(size_t)(nbase + i) * 5 + k];
        float v[10];
#pragma unroll
        for (int j = 0; j < 10; j++) {
            float s = 0.f;
#pragma unroll
            for (int k = 0; k < 5; k++) s += xi[k] * W1[k * 10 + j];
            v[j] = s;
        }
        float4* row = (float4*)(h1p + i * RP);
        row[0] = make_float4(v[0], v[1], v[2], v[3]);
        row[1] = make_float4(v[4], v[5], v[6], v[7]);
        row[2] = make_float4(v[8], v[9], 0.f, 0.f);
    }
    __syncthreads();
    for (int e = tid; e < EPG; e += 1024)
        atomicAdd(&hist[dst[ebase + e] - nbase], 1);
    __syncthreads();
    {
        int b2 = tid * 2;
        int v0 = hist[b2], v1 = hist[b2 + 1];
        int s = v0 + v1;
        int incl = wave_incl_scan(s);
        if ((tid & 63) == 63) wsumL[wid] = incl;
        __syncthreads();
        int pre = 0;
#pragma unroll
        for (int w = 0; w < 16; w++) { int t = wsumL[w]; if (w < wid) pre += t; }
        int base = pre + incl - s;
        rsL[b2] = base;
        rsL[b2 + 1] = base + v0;
        h1p[b2 * RP + 10] = rsqrtf((float)v0 + 1.0f);
        h1p[(b2 + 1) * RP + 10] = rsqrtf((float)v1 + 1.0f);
        hist[b2] = 0; hist[b2 + 1] = 0;
    }
    __syncthreads();
    for (int e = tid; e < EPG; e += 1024) {
        int ee = ebase + e;
        int sl = src[ee] - nbase;
        int dl = dst[ee] - nbase;
        int pos = rsL[dl] + atomicAdd(&hist[dl], 1);
        csrL[pos] = (unsigned short)sl;
    }
    __syncthreads();

    // ---- Phase B (dual-node gather; x1 in place + global copy; pr -> hist region)
    {
        int i0 = tid, i1 = tid + 1024;
        int e0 = rsL[i0], e0e = rsL[i0 + 1];
        int e1 = rsL[i1], e1e = (i1 == NPG - 1) ? EPG : rsL[i1 + 1];
        float acc0[10], acc1[10];
#pragma unroll
        for (int j = 0; j < 10; j++) { acc0[j] = 0.f; acc1[j] = 0.f; }
        while (e0 < e0e || e1 < e1e) {
            if (e0 < e0e) {
                int s = csrL[e0++];
                const float4* rw = (const float4*)(h1p + s * RP);
                float4 r0 = rw[0], r1 = rw[1], r2 = rw[2];
                float dv = r2.z;
                acc0[0] += r0.x * dv; acc0[1] += r0.y * dv; acc0[2] += r0.z * dv; acc0[3] += r0.w * dv;
                acc0[4] += r1.x * dv; acc0[5] += r1.y * dv; acc0[6] += r1.z * dv; acc0[7] += r1.w * dv;
                acc0[8] += r2.x * dv; acc0[9] += r2.y * dv;
            }
            if (e1 < e1e) {
                int s = csrL[e1++];
                const float4* rw = (const float4*)(h1p + s * RP);
                float4 r0 = rw[0], r1 = rw[1], r2 = rw[2];
                float dv = r2.z;
                acc1[0] += r0.x * dv; acc1[1] += r0.y * dv; acc1[2] += r0.z * dv; acc1[3] += r0.w * dv;
                acc1[4] += r1.x * dv; acc1[5] += r1.y * dv; acc1[6] += r1.z * dv; acc1[7] += r1.w * dv;
                acc1[8] += r2.x * dv; acc1[9] += r2.y * dv;
            }
        }
        const float4* q0 = (const float4*)(h1p + i0 * RP);
        const float4* q1 = (const float4*)(h1p + i1 * RP);
        float4 s00 = q0[0], s01 = q0[1], s02 = q0[2];
        float4 s10 = q1[0], s11 = q1[1], s12 = q1[2];
        float di0 = s02.z, d20 = di0 * di0;
        float di1 = s12.z, d21 = di1 * di1;
        float b1r[10];
#pragma unroll
        for (int j = 0; j < 10; j++) b1r[j] = b1[j];
        float v0[10], v1[10];
        v0[0] = acc0[0] * di0 + s00.x * d20 + b1r[0];
        v0[1] = acc0[1] * di0 + s00.y * d20 + b1r[1];
        v0[2] = acc0[2] * di0 + s00.z * d20 + b1r[2];
        v0[3] = acc0[3] * di0 + s00.w * d20 + b1r[3];
        v0[4] = acc0[4] * di0 + s01.x * d20 + b1r[4];
        v0[5] = acc0[5] * di0 + s01.y * d20 + b1r[5];
        v0[6] = acc0[6] * di0 + s01.z * d20 + b1r[6];
        v0[7] = acc0[7] * di0 + s01.w * d20 + b1r[7];
        v0[8] = acc0[8] * di0 + s02.x * d20 + b1r[8];
        v0[9] = acc0[9] * di0 + s02.y * d20 + b1r[9];
        v1[0] = acc1[0] * di1 + s10.x * d21 + b1r[0];
        v1[1] = acc1[1] * di1 + s10.y * d21 + b1r[1];
        v1[2] = acc1[2] * di1 + s10.z * d21 + b1r[2];
        v1[3] = acc1[3] * di1 + s10.w * d21 + b1r[3];
        v1[4] = acc1[4] * di1 + s11.x * d21 + b1r[4];
        v1[5] = acc1[5] * di1 + s11.y * d21 + b1r[5];
        v1[6] = acc1[6] * di1 + s11.z * d21 + b1r[6];
        v1[7] = acc1[7] * di1 + s11.w * d21 + b1r[7];
        v1[8] = acc1[8] * di1 + s12.x * d21 + b1r[8];
        v1[9] = acc1[9] * di1 + s12.y * d21 + b1r[9];
        float hs0 = 0.f, hs1 = 0.f;
#pragma unroll
        for (int j = 0; j < 10; j++) { float w = Ws[j]; hs0 += v0[j] * w; hs1 += v1[j] * w; }
        __syncthreads();
        float4* w0 = (float4*)(h1p + i0 * RP);
        w0[0] = make_float4(v0[0], v0[1], v0[2], v0[3]);
        w0[1] = make_float4(v0[4], v0[5], v0[6], v0[7]);
        w0[2] = make_float4(v0[8], v0[9], di0, hs0);
        float4* w1 = (float4*)(h1p + i1 * RP);
        w1[0] = make_float4(v1[0], v1[1], v1[2], v1[3]);
        w1[1] = make_float4(v1[4], v1[5], v1[6], v1[7]);
        w1[2] = make_float4(v1[8], v1[9], di1, hs1);
        prB[i0] = hs0 * di0;
        prB[i1] = hs1 * di1;
        // publish x1 rows for k_efgh (fire-and-forget stores)
        float4* g0 = (float4*)(x1g + (size_t)(nbase + i0) * RP);
        g0[0] = w0[0]; g0[1] = w0[1]; g0[2] = make_float4(v0[8], v0[9], di0, hs0);
        float4* g1 = (float4*)(x1g + (size_t)(nbase + i1) * RP);
        g1[0] = w1[0]; g1[1] = w1[1]; g1[2] = make_float4(v1[8], v1[9], di1, hs1);
    }
    __syncthreads();

    // ---- Phase C: scorer gather; keys -> global
    {
        float bsv = bs[0];
        int i0 = tid, i1 = tid + 1024;
        float2 own0 = *(const float2*)(h1p + i0 * RP + 10);
        float2 own1 = *(const float2*)(h1p + i1 * RP + 10);
        int e0 = rsL[i0], e0e = rsL[i0 + 1];
        int e1 = rsL[i1], e1e = (i1 == NPG - 1) ? EPG : rsL[i1 + 1];
        float a0 = 0.f, a1 = 0.f;
        while (e0 < e0e || e1 < e1e) {
            if (e0 < e0e) a0 += prB[csrL[e0++]];
            if (e1 < e1e) a1 += prB[csrL[e1++]];
        }
        float sc0 = own0.x * a0 + own0.y * own0.x * own0.x + bsv;
        float sc1 = own1.x * a1 + own1.y * own1.x * own1.x + bsv;
        unsigned u0 = __float_as_uint(sc0);
        unsigned u1 = __float_as_uint(sc1);
        keysG[nbase + i0] = (u0 & 0x80000000u) ? ~u0 : (u0 | 0x80000000u);
        keysG[nbase + i1] = (u1 & 0x80000000u) ? ~u1 : (u1 | 0x80000000u);
    }
}

// ================= k_sel: phase D (radix top-K select) =================
__global__ __launch_bounds__(1024) void k_sel(
    const unsigned* __restrict__ keysG, unsigned short* __restrict__ permG,
    unsigned short* __restrict__ newlG)
{
    __shared__ __align__(16) char arena[S_SZ];
    unsigned*       skL   = (unsigned*)(arena + S_SK);
    int*            hist  = (int*)(arena + S_HIST);
    unsigned short* newLs = (unsigned short*)(arena + S_NEWL);
    unsigned short* permL = (unsigned short*)(arena + S_PERM);
    int*            wsumL = (int*)(arena + S_WSUM);
    int*            flags = (int*)(arena + S_FLAG);
#define bselS  flags[0]
#define bneedS flags[1]

    int g = blockIdx.x, tid = threadIdx.x, wid = tid >> 6;
    int nbase = g * NPG;

    for (int i = tid; i < NPG; i += 1024) {
        skL[i] = keysG[nbase + i];
        newLs[i] = 0xFFFFu;
        hist[i] = 0;
    }
    int need = KSEL;
    unsigned prefix = 0;
    __syncthreads();
    for (int lv = 0; lv < 3; lv++) {
        for (int i = tid; i < NPG; i += 1024) {
            unsigned k = skL[i];
            bool match; unsigned bb;
            if (lv == 0)      { match = true;                  bb = k >> 21; }
            else if (lv == 1) { match = ((k >> 21) == prefix); bb = (k >> 10) & 0x7FFu; }
            else              { match = ((k >> 10) == prefix); bb = k & 0x3FFu; }
            if (match) atomicAdd(&hist[bb], 1);
        }
        __syncthreads();
        int b2 = tid * 2;
        int v0 = hist[b2], v1 = hist[b2 + 1];
        hist[b2] = 0; hist[b2 + 1] = 0;
        int s = v0 + v1;
        int incl = wave_incl_scan(s);
        if ((tid & 63) == 63) wsumL[wid] = incl;
        __syncthreads();
        int pre = 0, tot = 0;
#pragma unroll
        for (int w = 0; w < 16; w++) { int t = wsumL[w]; if (w < wid) pre += t; tot += t; }
        int base = pre + incl - s;
        { int Sb = tot - base;        int Sb1 = Sb - v0; if (Sb >= need && Sb1 < need) { bselS = b2;     bneedS = need - Sb1; } }
        { int Sb = tot - (base + v0); int Sb1 = Sb - v1; if (Sb >= need && Sb1 < need) { bselS = b2 + 1; bneedS = need - Sb1; } }
        __syncthreads();
        if (lv == 0)      prefix = (unsigned)bselS;
        else if (lv == 1) prefix = (prefix << 11) | (unsigned)bselS;
        else              prefix = (prefix << 10) | (unsigned)bselS;
        need = bneedS;
    }
    unsigned T = prefix;
    int greaterCnt = KSEL - need;
    {
        int b2 = tid * 2;
        unsigned k0 = skL[b2], k1 = skL[b2 + 1];
        int gt0 = k0 > T ? 1 : 0, gt1 = k1 > T ? 1 : 0;
        int eq0 = k0 == T ? 1 : 0, eq1 = k1 == T ? 1 : 0;
        int pack = ((gt0 + gt1) << 16) | (eq0 + eq1);
        int incl = wave_incl_scan(pack);
        if ((tid & 63) == 63) wsumL[wid] = incl;
        __syncthreads();
        int pre = 0;
#pragma unroll
        for (int w = 0; w < 16; w++) { int t = wsumL[w]; if (w < wid) pre += t; }
        int base = pre + incl - pack;
        int gb = base >> 16, eb = base & 0xFFFF;
        if (gt0) { permL[gb] = (unsigned short)b2; newLs[b2] = (unsigned short)gb; }
        if (gt1) { int r = gb + gt0; permL[r] = (unsigned short)(b2 + 1); newLs[b2 + 1] = (unsigned short)r; }
        if (eq0 && eb < need) { int p = greaterCnt + eb; permL[p] = (unsigned short)b2; newLs[b2] = (unsigned short)p; }
        if (eq1) { int r = eb + eq0; if (r < need) { int p = greaterCnt + r; permL[p] = (unsigned short)(b2 + 1); newLs[b2 + 1] = (unsigned short)p; } }
    }
    __syncthreads();
    for (int i = tid; i < NPG; i += 1024) newlG[nbase + i] = newLs[i];
    if (tid < KSEL) permG[(size_t)g * 512 + tid] = permL[tid];
}

// ================= k_efgh: phases E..H =================
__global__ __launch_bounds__(1024) void k_efgh(
    const int* __restrict__ src, const int* __restrict__ dst,
    const float* __restrict__ x1g, const unsigned* __restrict__ keysG,
    const unsigned short* __restrict__ permG, const unsigned short* __restrict__ newlG,
    const float* __restrict__ Wg, const float* __restrict__ a_srcw,
    const float* __restrict__ a_dstw, const float* __restrict__ bg,
    const float* __restrict__ Wf1, const float* __restrict__ bf1,
    const float* __restrict__ Wf2, const float* __restrict__ bf2,
    float* __restrict__ out)
{
    __shared__ __align__(16) char arena[E_SZ];
    float*          xpL   = (float*)(arena + E_XP);
    unsigned short* fadjL = (unsigned short*)(arena + E_FADJ);
    int*            fcntL = (int*)(arena + E_FCNT);
    float*          hfL   = (float*)(arena + E_HF);
    unsigned short* newLs = (unsigned short*)(arena + E_NEWL);
    unsigned short* permL = (unsigned short*)(arena + E_PERM);
    float*          alsL  = (float*)(arena + E_ALS);
    float*          aldL  = (float*)(arena + E_ALD);
    float*          wred  = (float*)(arena + E_WRED);
    float*          goutL = (float*)(arena + E_GOUT);
    float*          hidL  = (float*)(arena + E_HID);

    int g = blockIdx.x, tid = threadIdx.x, wid = tid >> 6;
    int nbase = g * NPG, ebase = g * EPG;

    // stage perm/newL; zero fcnt
    for (int i = tid; i < NPG; i += 1024) newLs[i] = newlG[nbase + i];
    if (tid < KSEL) { permL[tid] = permG[(size_t)g * 512 + tid]; fcntL[tid] = 0; }
    __syncthreads();

    // ---- E2: gated pooled features from global x1 rows
    if (tid < KSEL) {
        int iL = permL[tid];
        unsigned k = keysG[nbase + iL];
        unsigned u = (k & 0x80000000u) ? (k & 0x7FFFFFFFu) : ~k;
        float tt = tanhf(__uint_as_float(u));
        const float4* xr = (const float4*)(x1g + (size_t)(nbase + iL) * RP);
        float4 q0 = xr[0], q1 = xr[1], q2 = xr[2];
        float* xp = xpL + tid * 10;
        xp[0] = q0.x * tt; xp[1] = q0.y * tt; xp[2] = q0.z * tt; xp[3] = q0.w * tt;
        xp[4] = q1.x * tt; xp[5] = q1.y * tt; xp[6] = q1.z * tt; xp[7] = q1.w * tt;
        xp[8] = q2.x * tt; xp[9] = q2.y * tt;
    }
    // ---- E1: filtered adjacency by edge scan (same class as r1-k2 P6, passed)
    for (int e = tid; e < EPG; e += 1024) {
        int ee = ebase + e;
        unsigned short s2 = newLs[src[ee] - nbase];
        unsigned short d2 = newLs[dst[ee] - nbase];
        if (s2 != 0xFFFFu && d2 != 0xFFFFu) {
            int c = atomicAdd(&fcntL[d2], 1);
            if (c < FCAP) fadjL[d2 * FCAP + c] = s2;
        }
    }
    __syncthreads();

    // ---- F: GAT features
    for (int t = tid; t < KSEL * NH; t += 1024) {
        int p = t / NH, hh = t - p * NH;
        float xi[10];
#pragma unroll
        for (int k = 0; k < 10; k++) xi[k] = xpL[p * 10 + k];
        float v[NC];
        float as_ = 0.f, ad_ = 0.f;
#pragma unroll
        for (int c = 0; c < NC; c++) {
            int j = hh * NC + c;
            float vv = 0.f;
#pragma unroll
            for (int k = 0; k < 10; k++) vv += xi[k] * Wg[k * HC + j];
            v[c] = vv;
            as_ += vv * a_srcw[j];
            ad_ += vv * a_dstw[j];
        }
        float4* hr = (float4*)(hfL + p * HC + hh * NC);
#pragma unroll
        for (int q = 0; q < 5; q++)
            hr[q] = make_float4(v[4 * q], v[4 * q + 1], v[4 * q + 2], v[4 * q + 3]);
        alsL[p * NH + hh] = as_;
        aldL[p * NH + hh] = ad_;
    }
    __syncthreads();

    // ---- G: online single-pass softmax agg + butterfly readout
    {
        float res[NC];
#pragma unroll
        for (int rnd = 0; rnd < 2; rnd++) {
            int task = rnd == 0 ? tid : 1024 + tid;
            bool on = rnd == 0 || tid < KPAD;
            int hh = task >> 9, p = task & (KPAD - 1);
            if (on) {
                if (p < KSEL) {
                    float aldp = aldL[p * NH + hh];
                    float lself = leaky(alsL[p * NH + hh] + aldp);
                    int c = fcntL[p]; if (c > FCAP) c = FCAP;
                    const float4* hp = (const float4*)(hfL + p * HC + hh * NC);
                    float4 r0 = hp[0], r1 = hp[1], r2 = hp[2], r3 = hp[3], r4 = hp[4];
                    float wsum = 1.f;
                    for (int e = 0; e < c; e++) {
                        int idx = fadjL[p * FCAP + e];
                        float w = __expf(leaky(alsL[idx * NH + hh] + aldp) - lself);
                        wsum += w;
                        const float4* hq = (const float4*)(hfL + idx * HC + hh * NC);
                        float4 t0 = hq[0], t1 = hq[1], t2 = hq[2], t3 = hq[3], t4 = hq[4];
                        r0.x += w * t0.x; r0.y += w * t0.y; r0.z += w * t0.z; r0.w += w * t0.w;
                        r1.x += w * t1.x; r1.y += w * t1.y; r1.z += w * t1.z; r1.w += w * t1.w;
                        r2.x += w * t2.x; r2.y += w * t2.y; r2.z += w * t2.z; r2.w += w * t2.w;
                        r3.x += w * t3.x; r3.y += w * t3.y; r3.z += w * t3.z; r3.w += w * t3.w;
                        r4.x += w * t4.x; r4.y += w * t4.y; r4.z += w * t4.z; r4.w += w * t4.w;
                    }
                    float inv = 1.f / wsum;
                    res[0] = r0.x * inv;  res[1] = r0.y * inv;  res[2] = r0.z * inv;  res[3] = r0.w * inv;
                    res[4] = r1.x * inv;  res[5] = r1.y * inv;  res[6] = r1.z * inv;  res[7] = r1.w * inv;
                    res[8] = r2.x * inv;  res[9] = r2.y * inv;  res[10] = r2.z * inv; res[11] = r2.w * inv;
                    res[12] = r3.x * inv; res[13] = r3.y * inv; res[14] = r3.z * inv; res[15] = r3.w * inv;
                    res[16] = r4.x * inv; res[17] = r4.y * inv; res[18] = r4.z * inv; res[19] = r4.w * inv;
                } else {
#pragma unroll
                    for (int cc = 0; cc < NC; cc++) res[cc] = 0.f;
                }
#pragma unroll
                for (int cc = 0; cc < NC; cc++) {
                    float v = res[cc];
#pragma unroll
                    for (int d = 1; d < 64; d <<= 1) v += __shfl_xor(v, d, 64);
                    res[cc] = v;
                }
                if ((tid & 63) == 0) {
                    int slot = rnd == 0 ? hh * 8 + (wid & 7) : 16 + wid;
#pragma unroll
                    for (int cc = 0; cc < NC; cc++) wred[slot * NC + cc] = res[cc];
                }
            }
        }
    }
    __syncthreads();
    if (tid < HC) {
        int hh = tid / NC, c = tid - hh * NC;
        float a = 0.f;
#pragma unroll
        for (int w = 0; w < 8; w++) a += wred[(hh * 8 + w) * NC + c];
        goutL[tid] = a + (float)KSEL * bg[tid];
    }
    __syncthreads();

    // ---- H: MLP + log_softmax
    if (tid < 30) {
        float s = bf1[tid];
#pragma unroll
        for (int k = 0; k < HC; k++) s += goutL[k] * Wf1[k * 30 + tid];
        hidL[tid] = s > 0.f ? s : 0.f;
    }
    __syncthreads();
    if (tid == 0) {
        float z[3];
#pragma unroll
        for (int j = 0; j < 3; j++) {
            float s = bf2[j];
            for (int k = 0; k < 30; k++) s += hidL[k] * Wf2[k * 3 + j];
            z[j] = s;
        }
        float m = fmaxf(z[0], fmaxf(z[1], z[2]));
        float lse = logf(expf(z[0] - m) + expf(z[1] - m) + expf(z[2] - m)) + m;
#pragma unroll
        for (int j = 0; j < 3; j++) out[g * 3 + j] = z[j] - lse;
    }
}

extern "C" void kernel_launch(void* const* d_in, const int* in_sizes, int n_in,
                              void* d_out, int out_size, void* d_ws, size_t ws_size,
                              hipStream_t stream) {
    const float* x     = (const float*)d_in[0];
    const int*   src   = (const int*)d_in[1];
    const int*   dst   = (const int*)d_in[2];
    const float* W1    = (const float*)d_in[4];
    const float* b1    = (const float*)d_in[5];
    const float* Ws    = (const float*)d_in[6];
    const float* bs    = (const float*)d_in[7];
    const float* Wg    = (const float*)d_in[8];
    const float* a_src = (const float*)d_in[9];
    const float* a_dst = (const float*)d_in[10];
    const float* bg    = (const float*)d_in[11];
    const float* Wf1   = (const float*)d_in[12];
    const float* bf1   = (const float*)d_in[13];
    const float* Wf2   = (const float*)d_in[14];
    const float* bf2   = (const float*)d_in[15];
    float* out = (float*)d_out;

    float*          x1g   = (float*)((char*)d_ws + WS_X1G);
    unsigned*       keysG = (unsigned*)((char*)d_ws + WS_KEYS);
    unsigned short* permG = (unsigned short*)((char*)d_ws + WS_PERM);
    unsigned short* newlG = (unsigned short*)((char*)d_ws + WS_NEWL);

    k_ab<<<G, 1024, 0, stream>>>(x, src, dst, W1, b1, Ws, bs, x1g, keysG);
    k_sel<<<G, 1024, 0, stream>>>(keysG, permG, newlG);
    k_efgh<<<G, 1024, 0, stream>>>(src, dst, x1g, keysG, permG, newlG,
                                   Wg, a_src, a_dst, bg, Wf1, bf1, Wf2, bf2, out);
}

// Round 10
// 131.940 us; speedup vs baseline: 1.1792x; 1.1792x over previous
//
#include <hip/hip_runtime.h>
#include <math.h>

#define G    64
#define NPG  2048
#define NTOT (G * NPG)          // 131072
#define EPG  (NPG * 8)          // 16384 edges per graph
#define KSEL 410
#define NH   3
#define NC   20
#define HC   60
#define FCAP 24
#define KPAD 512
#define RP   12                 // h1p padded row: h1/x1[0..9], dinv@10, hs@11 (48 B)

// ---- LDS arena (bytes). Phases: A csr+h1, B gcn10(in-place x1), C scorer,
//      D topk, E2 xp-stage, E1 fadj, F gat feat, G agg+readout, H mlp.
// hist region triple-duty: degree hist/cursors [A], pr=dinv*hs [B..C], radix bins [D].
// wred2 (group partials) overlays xp, which dies after F.
#define OFF_H1P   0             // 98304  h1p 2048x12f            [A..E2]
#define OFF_XP    0             // 16400  xp 410x10f              [E2..F]  (h1p head dead)
#define OFF_WRED2 0             // 15360  wred2 192x20f           [G]      (xp dead)
#define OFF_FADJ  16400         // 19680  fadj 410x24 u16         [E1..G]
#define OFF_FCNT  36080         // 1648   fcnt int                [E1..G]
#define OFF_HF    37728         // 98400  hf 410x60f              [F..G]
#define OFF_CSR   98304         // 32768  csr u16                 [A..E1]
#define OFF_HIST  131072        // 8192   hist[A] / pr[B..C] / bins[D]
#define OFF_RS    139264        // 8192   rs int                  [A..E1]
#define OFF_ALS   139264        // 4920   als                     [F..G]   (rs dead)
#define OFF_ALD   144184        // 4920   ald                     [F..G]
#define OFF_SK    147456        // 8192   sk u32                  [C..E2]
#define OFF_GOUT  151024        // 240    [G..H]                  (sk dead)
#define OFF_HID   151264        // 120    [H]
#define OFF_NEWL  155648        // 4096   newL u16                [C..E1]
#define OFF_PERML 159744        // 824    permL u16               [D..E2]
#define OFF_WSUM  160568        // 64
#define OFF_FLAGS 160632        // 16
#define ARENA_SZ  160648

__device__ inline float leaky(float x) { return x >= 0.f ? x : 0.2f * x; }

__device__ inline int wave_incl_scan(int v) {
    int lane = threadIdx.x & 63;
#pragma unroll
    for (int d = 1; d < 64; d <<= 1) {
        int t = __shfl_up(v, d, 64);
        if (lane >= d) v += t;
    }
    return v;
}

__global__ __launch_bounds__(1024, 4) void k_all(
    const float* __restrict__ x, const int* __restrict__ src, const int* __restrict__ dst,
    const float* __restrict__ W1, const float* __restrict__ b1,
    const float* __restrict__ Ws, const float* __restrict__ bs,
    const float* __restrict__ Wg, const float* __restrict__ a_srcw,
    const float* __restrict__ a_dstw, const float* __restrict__ bg,
    const float* __restrict__ Wf1, const float* __restrict__ bf1,
    const float* __restrict__ Wf2, const float* __restrict__ bf2,
    float* __restrict__ out)
{
    __shared__ __align__(16) char arena[ARENA_SZ];
    float*          h1p   = (float*)(arena + OFF_H1P);
    float*          xpL   = (float*)(arena + OFF_XP);
    float*          wred2 = (float*)(arena + OFF_WRED2);
    unsigned short* fadjL = (unsigned short*)(arena + OFF_FADJ);
    int*            fcntL = (int*)(arena + OFF_FCNT);
    float*          hfL   = (float*)(arena + OFF_HF);
    unsigned short* csrL  = (unsigned short*)(arena + OFF_CSR);
    int*            hist  = (int*)(arena + OFF_HIST);
    float*          prB   = (float*)(arena + OFF_HIST);   // aliases hist [B..C]
    int*            rsL   = (int*)(arena + OFF_RS);
    float*          alsL  = (float*)(arena + OFF_ALS);
    float*          aldL  = (float*)(arena + OFF_ALD);
    unsigned*       skL   = (unsigned*)(arena + OFF_SK);
    float*          goutL = (float*)(arena + OFF_GOUT);
    float*          hidL  = (float*)(arena + OFF_HID);
    unsigned short* newLs = (unsigned short*)(arena + OFF_NEWL);
    unsigned short* permL = (unsigned short*)(arena + OFF_PERML);
    int*            wsumL = (int*)(arena + OFF_WSUM);
    int*            flags = (int*)(arena + OFF_FLAGS);
#define bselS  flags[0]
#define bneedS flags[1]

    int g = blockIdx.x, tid = threadIdx.x, wid = tid >> 6;
    int nbase = g * NPG, ebase = g * EPG;

    // ---- Phase A: zero hist; h1 -> LDS (padded rows, vector writes)
    for (int i = tid; i < NPG; i += 1024) hist[i] = 0;
    for (int i = tid; i < NPG; i += 1024) {
        float xi[5];
#pragma unroll
        for (int k = 0; k < 5; k++) xi[k] = x[(size_t)(nbase + i) * 5 + k];
        float v[10];
#pragma unroll
        for (int j = 0; j < 10; j++) {
            float s = 0.f;
#pragma unroll
            for (int k = 0; k < 5; k++) s += xi[k] * W1[k * 10 + j];
            v[j] = s;
        }
        float4* row = (float4*)(h1p + i * RP);
        row[0] = make_float4(v[0], v[1], v[2], v[3]);
        row[1] = make_float4(v[4], v[5], v[6], v[7]);
        row[2] = make_float4(v[8], v[9], 0.f, 0.f);   // slots 10/11 rewritten later
    }
    __syncthreads();
    for (int e = tid; e < EPG; e += 1024)
        atomicAdd(&hist[dst[ebase + e] - nbase], 1);
    __syncthreads();
    {   // exclusive scan, redundant-prefix; dinv -> slot 10
        int b2 = tid * 2;
        int v0 = hist[b2], v1 = hist[b2 + 1];
        int s = v0 + v1;
        int incl = wave_incl_scan(s);
        if ((tid & 63) == 63) wsumL[wid] = incl;
        __syncthreads();
        int pre = 0;
#pragma unroll
        for (int w = 0; w < 16; w++) { int t = wsumL[w]; if (w < wid) pre += t; }
        int base = pre + incl - s;
        rsL[b2] = base;
        rsL[b2 + 1] = base + v0;
        h1p[b2 * RP + 10] = rsqrtf((float)v0 + 1.0f);
        h1p[(b2 + 1) * RP + 10] = rsqrtf((float)v1 + 1.0f);
        hist[b2] = 0; hist[b2 + 1] = 0;              // cursors
    }
    __syncthreads();
    for (int e = tid; e < EPG; e += 1024) {
        int ee = ebase + e;
        int sl = src[ee] - nbase;
        int dl = dst[ee] - nbase;
        int pos = rsL[dl] + atomicAdd(&hist[dl], 1);
        csrL[pos] = (unsigned short)sl;
    }
    __syncthreads();

    // ---- Phase B: GCN10 gather, dual-node; x1 in place; pr=dinv*hs -> hist region
    {
        int i0 = tid, i1 = tid + 1024;
        int e0 = rsL[i0], e0e = rsL[i0 + 1];
        int e1 = rsL[i1], e1e = (i1 == NPG - 1) ? EPG : rsL[i1 + 1];
        float acc0[10], acc1[10];
#pragma unroll
        for (int j = 0; j < 10; j++) { acc0[j] = 0.f; acc1[j] = 0.f; }
        while (e0 < e0e || e1 < e1e) {
            if (e0 < e0e) {
                int s = csrL[e0++];
                const float4* rw = (const float4*)(h1p + s * RP);
                float4 r0 = rw[0], r1 = rw[1], r2 = rw[2];
                float dv = r2.z;
                acc0[0] += r0.x * dv; acc0[1] += r0.y * dv; acc0[2] += r0.z * dv; acc0[3] += r0.w * dv;
                acc0[4] += r1.x * dv; acc0[5] += r1.y * dv; acc0[6] += r1.z * dv; acc0[7] += r1.w * dv;
                acc0[8] += r2.x * dv; acc0[9] += r2.y * dv;
            }
            if (e1 < e1e) {
                int s = csrL[e1++];
                const float4* rw = (const float4*)(h1p + s * RP);
                float4 r0 = rw[0], r1 = rw[1], r2 = rw[2];
                float dv = r2.z;
                acc1[0] += r0.x * dv; acc1[1] += r0.y * dv; acc1[2] += r0.z * dv; acc1[3] += r0.w * dv;
                acc1[4] += r1.x * dv; acc1[5] += r1.y * dv; acc1[6] += r1.z * dv; acc1[7] += r1.w * dv;
                acc1[8] += r2.x * dv; acc1[9] += r2.y * dv;
            }
        }
        const float4* q0 = (const float4*)(h1p + i0 * RP);
        const float4* q1 = (const float4*)(h1p + i1 * RP);
        float4 s00 = q0[0], s01 = q0[1], s02 = q0[2];
        float4 s10 = q1[0], s11 = q1[1], s12 = q1[2];
        float di0 = s02.z, d20 = di0 * di0;
        float di1 = s12.z, d21 = di1 * di1;
        float b1r[10];
#pragma unroll
        for (int j = 0; j < 10; j++) b1r[j] = b1[j];
        float v0[10], v1[10];
        v0[0] = acc0[0] * di0 + s00.x * d20 + b1r[0];
        v0[1] = acc0[1] * di0 + s00.y * d20 + b1r[1];
        v0[2] = acc0[2] * di0 + s00.z * d20 + b1r[2];
        v0[3] = acc0[3] * di0 + s00.w * d20 + b1r[3];
        v0[4] = acc0[4] * di0 + s01.x * d20 + b1r[4];
        v0[5] = acc0[5] * di0 + s01.y * d20 + b1r[5];
        v0[6] = acc0[6] * di0 + s01.z * d20 + b1r[6];
        v0[7] = acc0[7] * di0 + s01.w * d20 + b1r[7];
        v0[8] = acc0[8] * di0 + s02.x * d20 + b1r[8];
        v0[9] = acc0[9] * di0 + s02.y * d20 + b1r[9];
        v1[0] = acc1[0] * di1 + s10.x * d21 + b1r[0];
        v1[1] = acc1[1] * di1 + s10.y * d21 + b1r[1];
        v1[2] = acc1[2] * di1 + s10.z * d21 + b1r[2];
        v1[3] = acc1[3] * di1 + s10.w * d21 + b1r[3];
        v1[4] = acc1[4] * di1 + s11.x * d21 + b1r[4];
        v1[5] = acc1[5] * di1 + s11.y * d21 + b1r[5];
        v1[6] = acc1[6] * di1 + s11.z * d21 + b1r[6];
        v1[7] = acc1[7] * di1 + s11.w * d21 + b1r[7];
        v1[8] = acc1[8] * di1 + s12.x * d21 + b1r[8];
        v1[9] = acc1[9] * di1 + s12.y * d21 + b1r[9];
        float hs0 = 0.f, hs1 = 0.f;
#pragma unroll
        for (int j = 0; j < 10; j++) { float w = Ws[j]; hs0 += v0[j] * w; hs1 += v1[j] * w; }
        __syncthreads();   // all gathers complete before any in-place overwrite
        float4* w0 = (float4*)(h1p + i0 * RP);
        w0[0] = make_float4(v0[0], v0[1], v0[2], v0[3]);
        w0[1] = make_float4(v0[4], v0[5], v0[6], v0[7]);
        w0[2] = make_float4(v0[8], v0[9], di0, hs0);
        float4* w1 = (float4*)(h1p + i1 * RP);
        w1[0] = make_float4(v1[0], v1[1], v1[2], v1[3]);
        w1[1] = make_float4(v1[4], v1[5], v1[6], v1[7]);
        w1[2] = make_float4(v1[8], v1[9], di1, hs1);
        prB[i0] = hs0 * di0;
        prB[i1] = hs1 * di1;
    }
    __syncthreads();

    // ---- Phase C: scorer gather (single b32 pr read per edge); keys; init newL
    {
        float bsv = bs[0];
        int i0 = tid, i1 = tid + 1024;
        float2 own0 = *(const float2*)(h1p + i0 * RP + 10);   // dinv, hs
        float2 own1 = *(const float2*)(h1p + i1 * RP + 10);
        int e0 = rsL[i0], e0e = rsL[i0 + 1];
        int e1 = rsL[i1], e1e = (i1 == NPG - 1) ? EPG : rsL[i1 + 1];
        float a0 = 0.f, a1 = 0.f;
        while (e0 < e0e || e1 < e1e) {
            if (e0 < e0e) a0 += prB[csrL[e0++]];
            if (e1 < e1e) a1 += prB[csrL[e1++]];
        }
        float sc0 = own0.x * a0 + own0.y * own0.x * own0.x + bsv;
        float sc1 = own1.x * a1 + own1.y * own1.x * own1.x + bsv;
        unsigned u0 = __float_as_uint(sc0);
        unsigned u1 = __float_as_uint(sc1);
        skL[i0] = (u0 & 0x80000000u) ? ~u0 : (u0 | 0x80000000u);
        skL[i1] = (u1 & 0x80000000u) ? ~u1 : (u1 | 0x80000000u);
        newLs[i0] = 0xFFFFu; newLs[i1] = 0xFFFFu;
    }
    int need = KSEL;
    unsigned prefix = 0;
    __syncthreads();
    for (int i = tid; i < NPG; i += 1024) hist[i] = 0;   // radix bins (pr dead)
    __syncthreads();

    // ---- Phase D: 3-level radix select (redundant-prefix scans)
    for (int lv = 0; lv < 3; lv++) {
        for (int i = tid; i < NPG; i += 1024) {
            unsigned k = skL[i];
            bool match; unsigned bb;
            if (lv == 0)      { match = true;                  bb = k >> 21; }
            else if (lv == 1) { match = ((k >> 21) == prefix); bb = (k >> 10) & 0x7FFu; }
            else              { match = ((k >> 10) == prefix); bb = k & 0x3FFu; }
            if (match) atomicAdd(&hist[bb], 1);
        }
        __syncthreads();
        int b2 = tid * 2;
        int v0 = hist[b2], v1 = hist[b2 + 1];
        hist[b2] = 0; hist[b2 + 1] = 0;
        int s = v0 + v1;
        int incl = wave_incl_scan(s);
        if ((tid & 63) == 63) wsumL[wid] = incl;
        __syncthreads();
        int pre = 0, tot = 0;
#pragma unroll
        for (int w = 0; w < 16; w++) { int t = wsumL[w]; if (w < wid) pre += t; tot += t; }
        int base = pre + incl - s;
        { int Sb = tot - base;        int Sb1 = Sb - v0; if (Sb >= need && Sb1 < need) { bselS = b2;     bneedS = need - Sb1; } }
        { int Sb = tot - (base + v0); int Sb1 = Sb - v1; if (Sb >= need && Sb1 < need) { bselS = b2 + 1; bneedS = need - Sb1; } }
        __syncthreads();
        if (lv == 0)      prefix = (unsigned)bselS;
        else if (lv == 1) prefix = (prefix << 11) | (unsigned)bselS;
        else              prefix = (prefix << 10) | (unsigned)bselS;
        need = bneedS;
    }
    unsigned T = prefix;              // exact K-th largest key; need = #ties to take
    int greaterCnt = KSEL - need;

    // ---- Perm/newL: ONE packed scan (greater hi16, ties lo16), redundant-prefix
    {
        int b2 = tid * 2;
        unsigned k0 = skL[b2], k1 = skL[b2 + 1];
        int gt0 = k0 > T ? 1 : 0, gt1 = k1 > T ? 1 : 0;
        int eq0 = k0 == T ? 1 : 0, eq1 = k1 == T ? 1 : 0;
        int pack = ((gt0 + gt1) << 16) | (eq0 + eq1);
        int incl = wave_incl_scan(pack);
        if ((tid & 63) == 63) wsumL[wid] = incl;
        __syncthreads();
        int pre = 0;
#pragma unroll
        for (int w = 0; w < 16; w++) { int t = wsumL[w]; if (w < wid) pre += t; }
        int base = pre + incl - pack;
        int gb = base >> 16, eb = base & 0xFFFF;
        if (gt0) { permL[gb] = (unsigned short)b2; newLs[b2] = (unsigned short)gb; }
        if (gt1) { int r = gb + gt0; permL[r] = (unsigned short)(b2 + 1); newLs[b2 + 1] = (unsigned short)r; }
        if (eq0 && eb < need) { int p = greaterCnt + eb; permL[p] = (unsigned short)b2; newLs[b2] = (unsigned short)p; }
        if (eq1) { int r = eb + eq0; if (r < need) { int p = greaterCnt + r; permL[p] = (unsigned short)(b2 + 1); newLs[b2 + 1] = (unsigned short)p; } }
    }
    __syncthreads();

    // ---- Phase E2: gated pooled features, reg-staged; xp over h1p head
    {
        float4 rq0, rq1, rq2; float tt = 0.f;
        bool havep = (tid < KSEL);
        if (havep) {
            int iL = permL[tid];
            unsigned k = skL[iL];
            unsigned u = (k & 0x80000000u) ? (k & 0x7FFFFFFFu) : ~k;
            tt = tanhf(__uint_as_float(u));
            const float4* xr = (const float4*)(h1p + iL * RP);
            rq0 = xr[0]; rq1 = xr[1]; rq2 = xr[2];
        }
        __syncthreads();   // all x1 reads complete before xp overwrites h1p head
        if (havep) {
            float* xp = xpL + tid * 10;
            xp[0] = rq0.x * tt; xp[1] = rq0.y * tt; xp[2] = rq0.z * tt; xp[3] = rq0.w * tt;
            xp[4] = rq1.x * tt; xp[5] = rq1.y * tt; xp[6] = rq1.z * tt; xp[7] = rq1.w * tt;
            xp[8] = rq2.x * tt; xp[9] = rq2.y * tt;
        }
    }
    __syncthreads();

    // ---- Phase E1: filtered adjacency, chunk-of-8 prefetch
    for (int p = tid; p < KSEL; p += 1024) {
        int iL = permL[p];
        int p0 = rsL[iL], p1 = (iL == NPG - 1) ? EPG : rsL[iL + 1];
        int c = 0;
        int e = p0;
        while (e < p1) {
            int n = p1 - e; n = n > 8 ? 8 : n;
            int b8[8];
#pragma unroll
            for (int j = 0; j < 8; j++) b8[j] = csrL[e + (j < n ? j : 0)];
            unsigned short n8[8];
#pragma unroll
            for (int j = 0; j < 8; j++) n8[j] = newLs[b8[j]];
#pragma unroll
            for (int j = 0; j < 8; j++)
                if (j < n && n8[j] != 0xFFFFu && c < FCAP) fadjL[p * FCAP + c++] = n8[j];
            e += n;
        }
        fcntL[p] = c;
    }
    __syncthreads();

    // ---- Phase F: GAT features, wave-uniform head -> scalar Wg/a loads
    for (int rnd = 0; rnd < 2; rnd++) {
        int task = rnd == 0 ? tid : 1024 + tid;
        bool on = rnd == 0 || tid < KPAD;
        if (on) {
            int hh = __builtin_amdgcn_readfirstlane(task >> 9);   // wave-uniform head
            int p = task & (KPAD - 1);
            if (p < KSEL) {
                float xi[10];
#pragma unroll
                for (int k = 0; k < 10; k++) xi[k] = xpL[p * 10 + k];
                float v[NC];
                float as_ = 0.f, ad_ = 0.f;
#pragma unroll
                for (int c = 0; c < NC; c++) {
                    int j = hh * NC + c;
                    float vv = 0.f;
#pragma unroll
                    for (int k = 0; k < 10; k++) vv += xi[k] * Wg[k * HC + j];
                    v[c] = vv;
                    as_ += vv * a_srcw[j];
                    ad_ += vv * a_dstw[j];
                }
                float4* hr = (float4*)(hfL + p * HC + hh * NC);
#pragma unroll
                for (int q = 0; q < 5; q++)
                    hr[q] = make_float4(v[4 * q], v[4 * q + 1], v[4 * q + 2], v[4 * q + 3]);
                alsL[p * NH + hh] = as_;
                aldL[p * NH + hh] = ad_;
            }
        }
    }
    __syncthreads();

    // ---- Phase G: online single-pass softmax agg + butterfly-lite readout
    // 3-step shfl (sum over 8-lane group) + group partials in wred2 (xp dead),
    // then one 60-thread final pass. -1440 DS-pipe ops vs 6-step butterfly.
    {
        float res[NC];
#pragma unroll
        for (int rnd = 0; rnd < 2; rnd++) {
            int task = rnd == 0 ? tid : 1024 + tid;
            bool on = rnd == 0 || tid < KPAD;
            int hh = task >> 9, p = task & (KPAD - 1);
            if (on) {
                if (p < KSEL) {
                    float aldp = aldL[p * NH + hh];
                    float lself = leaky(alsL[p * NH + hh] + aldp);
                    int c = fcntL[p];
                    const float4* hp = (const float4*)(hfL + p * HC + hh * NC);
                    float4 r0 = hp[0], r1 = hp[1], r2 = hp[2], r3 = hp[3], r4 = hp[4];
                    float wsum = 1.f;   // self weight exp(lself-lself)=1
                    for (int e = 0; e < c; e++) {
                        int idx = fadjL[p * FCAP + e];
                        float w = __expf(leaky(alsL[idx * NH + hh] + aldp) - lself);
                        wsum += w;
                        const float4* hq = (const float4*)(hfL + idx * HC + hh * NC);
                        float4 t0 = hq[0], t1 = hq[1], t2 = hq[2], t3 = hq[3], t4 = hq[4];
                        r0.x += w * t0.x; r0.y += w * t0.y; r0.z += w * t0.z; r0.w += w * t0.w;
                        r1.x += w * t1.x; r1.y += w * t1.y; r1.z += w * t1.z; r1.w += w * t1.w;
                        r2.x += w * t2.x; r2.y += w * t2.y; r2.z += w * t2.z; r2.w += w * t2.w;
                        r3.x += w * t3.x; r3.y += w * t3.y; r3.z += w * t3.z; r3.w += w * t3.w;
                        r4.x += w * t4.x; r4.y += w * t4.y; r4.z += w * t4.z; r4.w += w * t4.w;
                    }
                    float inv = 1.f / wsum;
                    res[0] = r0.x * inv;  res[1] = r0.y * inv;  res[2] = r0.z * inv;  res[3] = r0.w * inv;
                    res[4] = r1.x * inv;  res[5] = r1.y * inv;  res[6] = r1.z * inv;  res[7] = r1.w * inv;
                    res[8] = r2.x * inv;  res[9] = r2.y * inv;  res[10] = r2.z * inv; res[11] = r2.w * inv;
                    res[12] = r3.x * inv; res[13] = r3.y * inv; res[14] = r3.z * inv; res[15] = r3.w * inv;
                    res[16] = r4.x * inv; res[17] = r4.y * inv; res[18] = r4.z * inv; res[19] = r4.w * inv;
                } else {
#pragma unroll
                    for (int cc = 0; cc < NC; cc++) res[cc] = 0.f;
                }
                // sum within aligned 8-lane group (p is lane-consecutive)
#pragma unroll
                for (int cc = 0; cc < NC; cc++) {
                    float v = res[cc];
                    v += __shfl_xor(v, 1, 64);
                    v += __shfl_xor(v, 2, 64);
                    v += __shfl_xor(v, 4, 64);
                    res[cc] = v;
                }
                if ((tid & 7) == 0) {
                    int slot = hh * 64 + (p >> 3);      // 0..191
                    float* gp = wred2 + slot * NC;
#pragma unroll
                    for (int cc = 0; cc < NC; cc++) gp[cc] = res[cc];
                }
            }
        }
    }
    __syncthreads();
    if (tid < HC) {
        int hh = tid / NC, c = tid - hh * NC;
        float a = 0.f;
        for (int w = 0; w < 64; w++) a += wred2[(hh * 64 + w) * NC + c];
        goutL[tid] = a + (float)KSEL * bg[tid];
    }
    __syncthreads();

    // ---- Phase H: MLP + log_softmax
    if (tid < 30) {
        float s = bf1[tid];
#pragma unroll
        for (int k = 0; k < HC; k++) s += goutL[k] * Wf1[k * 30 + tid];
        hidL[tid] = s > 0.f ? s : 0.f;
    }
    __syncthreads();
    if (tid == 0) {
        float z[3];
#pragma unroll
        for (int j = 0; j < 3; j++) {
            float s = bf2[j];
            for (int k = 0; k < 30; k++) s += hidL[k] * Wf2[k * 3 + j];
            z[j] = s;
        }
        float m = fmaxf(z[0], fmaxf(z[1], z[2]));
        float lse = logf(expf(z[0] - m) + expf(z[1] - m) + expf(z[2] - m)) + m;
#pragma unroll
        for (int j = 0; j < 3; j++) out[g * 3 + j] = z[j] - lse;
    }
}

extern "C" void kernel_launch(void* const* d_in, const int* in_sizes, int n_in,
                              void* d_out, int out_size, void* d_ws, size_t ws_size,
                              hipStream_t stream) {
    const float* x     = (const float*)d_in[0];
    const int*   src   = (const int*)d_in[1];
    const int*   dst   = (const int*)d_in[2];
    const float* W1    = (const float*)d_in[4];
    const float* b1    = (const float*)d_in[5];
    const float* Ws    = (const float*)d_in[6];
    const float* bs    = (const float*)d_in[7];
    const float* Wg    = (const float*)d_in[8];
    const float* a_src = (const float*)d_in[9];
    const float* a_dst = (const float*)d_in[10];
    const float* bg    = (const float*)d_in[11];
    const float* Wf1   = (const float*)d_in[12];
    const float* bf1   = (const float*)d_in[13];
    const float* Wf2   = (const float*)d_in[14];
    const float* bf2   = (const float*)d_in[15];
    float* out = (float*)d_out;
    (void)d_ws; (void)ws_size;   // no workspace: avoids the 41 us harness re-poison fill

    k_all<<<G, 1024, 0, stream>>>(x, src, dst, W1, b1, Ws, bs, Wg, a_src, a_dst,
                                  bg, Wf1, bf1, Wf2, bf2, out);
}

// Round 11
// 129.052 us; speedup vs baseline: 1.2056x; 1.0224x over previous
//
#include <hip/hip_runtime.h>
#include <math.h>

#define G    64
#define NPG  2048
#define NTOT (G * NPG)          // 131072
#define EPG  (NPG * 8)          // 16384 edges per graph
#define KSEL 410
#define NH   3
#define NC   20
#define HC   60
#define FCAP 24
#define KPAD 512
#define RP   12                 // row: x/x1[0..9], dinv@10, hs@11 (48 B); dinv dup @5 in A..B

// ---- LDS arena (bytes). Phases: A csr+stage-x, B gcn10(linearity, in-place x1),
//      C scorer, D topk, E2 xp-stage, E1 fadj, F gat feat, G agg+readout, H mlp.
// hist region triple-duty: degree hist/cursors [A], pr=dinv*hs [B..C], radix bins [D].
// wred2 (group partials) overlays xp, which dies after F.
#define OFF_H1P   0             // 98304  rows 2048x12f           [A..E2]
#define OFF_XP    0             // 16400  xp 410x10f              [E2..F]  (row head dead)
#define OFF_WRED2 0             // 15360  wred2 192x20f           [G]      (xp dead)
#define OFF_FADJ  16400         // 19680  fadj 410x24 u16         [E1..G]
#define OFF_FCNT  36080         // 1648   fcnt int                [E1..G]
#define OFF_HF    37728         // 98400  hf 410x60f              [F..G]
#define OFF_CSR   98304         // 32768  csr u16                 [A..E1]
#define OFF_HIST  131072        // 8192   hist[A] / pr[B..C] / bins[D]
#define OFF_RS    139264        // 8192   rs int                  [A..E1]
#define OFF_ALS   139264        // 4920   als                     [F..G]   (rs dead)
#define OFF_ALD   144184        // 4920   ald                     [F..G]
#define OFF_SK    147456        // 8192   sk u32                  [C..E2]
#define OFF_GOUT  151024        // 240    [G..H]                  (sk dead)
#define OFF_HID   151264        // 120    [H]
#define OFF_NEWL  155648        // 4096   newL u16                [C..E1]
#define OFF_PERML 159744        // 824    permL u16               [D..E2]
#define OFF_WSUM  160568        // 64
#define OFF_FLAGS 160632        // 16
#define ARENA_SZ  160648

__device__ inline float leaky(float x) { return x >= 0.f ? x : 0.2f * x; }

__device__ inline int wave_incl_scan(int v) {
    int lane = threadIdx.x & 63;
#pragma unroll
    for (int d = 1; d < 64; d <<= 1) {
        int t = __shfl_up(v, d, 64);
        if (lane >= d) v += t;
    }
    return v;
}

__global__ __launch_bounds__(1024, 4) void k_all(
    const float* __restrict__ x, const int* __restrict__ src, const int* __restrict__ dst,
    const float* __restrict__ W1, const float* __restrict__ b1,
    const float* __restrict__ Ws, const float* __restrict__ bs,
    const float* __restrict__ Wg, const float* __restrict__ a_srcw,
    const float* __restrict__ a_dstw, const float* __restrict__ bg,
    const float* __restrict__ Wf1, const float* __restrict__ bf1,
    const float* __restrict__ Wf2, const float* __restrict__ bf2,
    float* __restrict__ out)
{
    __shared__ __align__(16) char arena[ARENA_SZ];
    float*          h1p   = (float*)(arena + OFF_H1P);
    float*          xpL   = (float*)(arena + OFF_XP);
    float*          wred2 = (float*)(arena + OFF_WRED2);
    unsigned short* fadjL = (unsigned short*)(arena + OFF_FADJ);
    int*            fcntL = (int*)(arena + OFF_FCNT);
    float*          hfL   = (float*)(arena + OFF_HF);
    unsigned short* csrL  = (unsigned short*)(arena + OFF_CSR);
    int*            hist  = (int*)(arena + OFF_HIST);
    float*          prB   = (float*)(arena + OFF_HIST);   // aliases hist [B..C]
    int*            rsL   = (int*)(arena + OFF_RS);
    float*          alsL  = (float*)(arena + OFF_ALS);
    float*          aldL  = (float*)(arena + OFF_ALD);
    unsigned*       skL   = (unsigned*)(arena + OFF_SK);
    float*          goutL = (float*)(arena + OFF_GOUT);
    float*          hidL  = (float*)(arena + OFF_HID);
    unsigned short* newLs = (unsigned short*)(arena + OFF_NEWL);
    unsigned short* permL = (unsigned short*)(arena + OFF_PERML);
    int*            wsumL = (int*)(arena + OFF_WSUM);
    int*            flags = (int*)(arena + OFF_FLAGS);
#define bselS  flags[0]
#define bneedS flags[1]

    int g = blockIdx.x, tid = threadIdx.x, wid = tid >> 6;
    int nbase = g * NPG, ebase = g * EPG;

    // ---- Phase A: zero hist; stage RAW x rows (no W1 yet — GCN linearity defers it)
    for (int i = tid; i < NPG; i += 1024) hist[i] = 0;
    for (int i = tid; i < NPG; i += 1024) {
        const float* xr = x + (size_t)(nbase + i) * 5;
        float x0 = xr[0], x1v = xr[1], x2 = xr[2], x3 = xr[3], x4 = xr[4];
        float4* row = (float4*)(h1p + i * RP);
        row[0] = make_float4(x0, x1v, x2, x3);
        row[1] = make_float4(x4, 0.f, 0.f, 0.f);   // slot5 = dinv (written in scan)
    }
    __syncthreads();
    for (int e = tid; e < EPG; e += 1024)
        atomicAdd(&hist[dst[ebase + e] - nbase], 1);
    __syncthreads();
    {   // exclusive scan, redundant-prefix; dinv -> slots 5 (gather) and 10 (C/E2)
        int b2 = tid * 2;
        int v0 = hist[b2], v1 = hist[b2 + 1];
        int s = v0 + v1;
        int incl = wave_incl_scan(s);
        if ((tid & 63) == 63) wsumL[wid] = incl;
        __syncthreads();
        int pre = 0;
#pragma unroll
        for (int w = 0; w < 16; w++) { int t = wsumL[w]; if (w < wid) pre += t; }
        int base = pre + incl - s;
        rsL[b2] = base;
        rsL[b2 + 1] = base + v0;
        float di0 = rsqrtf((float)v0 + 1.0f);
        float di1 = rsqrtf((float)v1 + 1.0f);
        h1p[b2 * RP + 5]        = di0;
        h1p[b2 * RP + 10]       = di0;
        h1p[(b2 + 1) * RP + 5]  = di1;
        h1p[(b2 + 1) * RP + 10] = di1;
        hist[b2] = 0; hist[b2 + 1] = 0;              // cursors
    }
    __syncthreads();
    for (int e = tid; e < EPG; e += 1024) {
        int ee = ebase + e;
        int sl = src[ee] - nbase;
        int dl = dst[ee] - nbase;
        int pos = rsL[dl] + atomicAdd(&hist[dl], 1);
        csrL[pos] = (unsigned short)sl;
    }
    __syncthreads();

    // ---- Phase B: 5-wide x gather (b128+b64/edge, 5 FMA) via linearity; W1 once/node;
    //      x1 written in place; pr=dinv*hs -> hist region
    {
        int i0 = tid, i1 = tid + 1024;
        int e0 = rsL[i0], e0e = rsL[i0 + 1];
        int e1 = rsL[i1], e1e = (i1 == NPG - 1) ? EPG : rsL[i1 + 1];
        float a0[5], a1[5];
#pragma unroll
        for (int j = 0; j < 5; j++) { a0[j] = 0.f; a1[j] = 0.f; }
        while (e0 < e0e || e1 < e1e) {
            if (e0 < e0e) {
                int s = csrL[e0++];
                float4 r0 = *(const float4*)(h1p + s * RP);
                float2 r1 = *(const float2*)(h1p + s * RP + 4);   // x4, dinv
                float dv = r1.y;
                a0[0] += r0.x * dv; a0[1] += r0.y * dv; a0[2] += r0.z * dv;
                a0[3] += r0.w * dv; a0[4] += r1.x * dv;
            }
            if (e1 < e1e) {
                int s = csrL[e1++];
                float4 r0 = *(const float4*)(h1p + s * RP);
                float2 r1 = *(const float2*)(h1p + s * RP + 4);
                float dv = r1.y;
                a1[0] += r0.x * dv; a1[1] += r0.y * dv; a1[2] += r0.z * dv;
                a1[3] += r0.w * dv; a1[4] += r1.x * dv;
            }
        }
        float4 s0 = *(const float4*)(h1p + i0 * RP);
        float2 s0b = *(const float2*)(h1p + i0 * RP + 4);
        float4 s1 = *(const float4*)(h1p + i1 * RP);
        float2 s1b = *(const float2*)(h1p + i1 * RP + 4);
        float di0 = s0b.y, d20 = di0 * di0;
        float di1 = s1b.y, d21 = di1 * di1;
        float y0[5], y1[5];
        y0[0] = a0[0] * di0 + s0.x * d20;
        y0[1] = a0[1] * di0 + s0.y * d20;
        y0[2] = a0[2] * di0 + s0.z * d20;
        y0[3] = a0[3] * di0 + s0.w * d20;
        y0[4] = a0[4] * di0 + s0b.x * d20;
        y1[0] = a1[0] * di1 + s1.x * d21;
        y1[1] = a1[1] * di1 + s1.y * d21;
        y1[2] = a1[2] * di1 + s1.z * d21;
        y1[3] = a1[3] * di1 + s1.w * d21;
        y1[4] = a1[4] * di1 + s1b.x * d21;
        // deferred W1: x1 = y5 @ W1 + b1  (uniform-address loads -> scalar, cached)
        float v0[10], v1[10];
#pragma unroll
        for (int k = 0; k < 10; k++) {
            float b = b1[k];
            float c0 = b, c1 = b;
#pragma unroll
            for (int j = 0; j < 5; j++) {
                float w = W1[j * 10 + k];
                c0 += y0[j] * w;
                c1 += y1[j] * w;
            }
            v0[k] = c0; v1[k] = c1;
        }
        float hs0 = 0.f, hs1 = 0.f;
#pragma unroll
        for (int k = 0; k < 10; k++) { float w = Ws[k]; hs0 += v0[k] * w; hs1 += v1[k] * w; }
        __syncthreads();   // all gathers complete before any in-place overwrite
        float4* w0 = (float4*)(h1p + i0 * RP);
        w0[0] = make_float4(v0[0], v0[1], v0[2], v0[3]);
        w0[1] = make_float4(v0[4], v0[5], v0[6], v0[7]);
        w0[2] = make_float4(v0[8], v0[9], di0, hs0);
        float4* w1 = (float4*)(h1p + i1 * RP);
        w1[0] = make_float4(v1[0], v1[1], v1[2], v1[3]);
        w1[1] = make_float4(v1[4], v1[5], v1[6], v1[7]);
        w1[2] = make_float4(v1[8], v1[9], di1, hs1);
        prB[i0] = hs0 * di0;
        prB[i1] = hs1 * di1;
    }
    __syncthreads();

    // ---- Phase C: scorer gather (single b32 pr read per edge); keys; init newL
    {
        float bsv = bs[0];
        int i0 = tid, i1 = tid + 1024;
        float2 own0 = *(const float2*)(h1p + i0 * RP + 10);   // dinv, hs
        float2 own1 = *(const float2*)(h1p + i1 * RP + 10);
        int e0 = rsL[i0], e0e = rsL[i0 + 1];
        int e1 = rsL[i1], e1e = (i1 == NPG - 1) ? EPG : rsL[i1 + 1];
        float a0 = 0.f, a1 = 0.f;
        while (e0 < e0e || e1 < e1e) {
            if (e0 < e0e) a0 += prB[csrL[e0++]];
            if (e1 < e1e) a1 += prB[csrL[e1++]];
        }
        float sc0 = own0.x * a0 + own0.y * own0.x * own0.x + bsv;
        float sc1 = own1.x * a1 + own1.y * own1.x * own1.x + bsv;
        unsigned u0 = __float_as_uint(sc0);
        unsigned u1 = __float_as_uint(sc1);
        skL[i0] = (u0 & 0x80000000u) ? ~u0 : (u0 | 0x80000000u);
        skL[i1] = (u1 & 0x80000000u) ? ~u1 : (u1 | 0x80000000u);
        newLs[i0] = 0xFFFFu; newLs[i1] = 0xFFFFu;
    }
    int need = KSEL;
    unsigned prefix = 0;
    __syncthreads();
    for (int i = tid; i < NPG; i += 1024) hist[i] = 0;   // radix bins (pr dead)
    __syncthreads();

    // ---- Phase D: 3-level radix select (redundant-prefix scans)
    for (int lv = 0; lv < 3; lv++) {
        for (int i = tid; i < NPG; i += 1024) {
            unsigned k = skL[i];
            bool match; unsigned bb;
            if (lv == 0)      { match = true;                  bb = k >> 21; }
            else if (lv == 1) { match = ((k >> 21) == prefix); bb = (k >> 10) & 0x7FFu; }
            else              { match = ((k >> 10) == prefix); bb = k & 0x3FFu; }
            if (match) atomicAdd(&hist[bb], 1);
        }
        __syncthreads();
        int b2 = tid * 2;
        int v0 = hist[b2], v1 = hist[b2 + 1];
        hist[b2] = 0; hist[b2 + 1] = 0;
        int s = v0 + v1;
        int incl = wave_incl_scan(s);
        if ((tid & 63) == 63) wsumL[wid] = incl;
        __syncthreads();
        int pre = 0, tot = 0;
#pragma unroll
        for (int w = 0; w < 16; w++) { int t = wsumL[w]; if (w < wid) pre += t; tot += t; }
        int base = pre + incl - s;
        { int Sb = tot - base;        int Sb1 = Sb - v0; if (Sb >= need && Sb1 < need) { bselS = b2;     bneedS = need - Sb1; } }
        { int Sb = tot - (base + v0); int Sb1 = Sb - v1; if (Sb >= need && Sb1 < need) { bselS = b2 + 1; bneedS = need - Sb1; } }
        __syncthreads();
        if (lv == 0)      prefix = (unsigned)bselS;
        else if (lv == 1) prefix = (prefix << 11) | (unsigned)bselS;
        else              prefix = (prefix << 10) | (unsigned)bselS;
        need = bneedS;
    }
    unsigned T = prefix;              // exact K-th largest key; need = #ties to take
    int greaterCnt = KSEL - need;

    // ---- Perm/newL: ONE packed scan (greater hi16, ties lo16), redundant-prefix
    {
        int b2 = tid * 2;
        unsigned k0 = skL[b2], k1 = skL[b2 + 1];
        int gt0 = k0 > T ? 1 : 0, gt1 = k1 > T ? 1 : 0;
        int eq0 = k0 == T ? 1 : 0, eq1 = k1 == T ? 1 : 0;
        int pack = ((gt0 + gt1) << 16) | (eq0 + eq1);
        int incl = wave_incl_scan(pack);
        if ((tid & 63) == 63) wsumL[wid] = incl;
        __syncthreads();
        int pre = 0;
#pragma unroll
        for (int w = 0; w < 16; w++) { int t = wsumL[w]; if (w < wid) pre += t; }
        int base = pre + incl - pack;
        int gb = base >> 16, eb = base & 0xFFFF;
        if (gt0) { permL[gb] = (unsigned short)b2; newLs[b2] = (unsigned short)gb; }
        if (gt1) { int r = gb + gt0; permL[r] = (unsigned short)(b2 + 1); newLs[b2 + 1] = (unsigned short)r; }
        if (eq0 && eb < need) { int p = greaterCnt + eb; permL[p] = (unsigned short)b2; newLs[b2] = (unsigned short)p; }
        if (eq1) { int r = eb + eq0; if (r < need) { int p = greaterCnt + r; permL[p] = (unsigned short)(b2 + 1); newLs[b2 + 1] = (unsigned short)p; } }
    }
    __syncthreads();

    // ---- Phase E2: gated pooled features, reg-staged; xp over row head
    {
        float4 rq0, rq1, rq2; float tt = 0.f;
        bool havep = (tid < KSEL);
        if (havep) {
            int iL = permL[tid];
            unsigned k = skL[iL];
            unsigned u = (k & 0x80000000u) ? (k & 0x7FFFFFFFu) : ~k;
            tt = tanhf(__uint_as_float(u));
            const float4* xr = (const float4*)(h1p + iL * RP);
            rq0 = xr[0]; rq1 = xr[1]; rq2 = xr[2];
        }
        __syncthreads();   // all x1 reads complete before xp overwrites row head
        if (havep) {
            float* xp = xpL + tid * 10;
            xp[0] = rq0.x * tt; xp[1] = rq0.y * tt; xp[2] = rq0.z * tt; xp[3] = rq0.w * tt;
            xp[4] = rq1.x * tt; xp[5] = rq1.y * tt; xp[6] = rq1.z * tt; xp[7] = rq1.w * tt;
            xp[8] = rq2.x * tt; xp[9] = rq2.y * tt;
        }
    }
    __syncthreads();

    // ---- Phase E1: filtered adjacency, chunk-of-8 prefetch
    for (int p = tid; p < KSEL; p += 1024) {
        int iL = permL[p];
        int p0 = rsL[iL], p1 = (iL == NPG - 1) ? EPG : rsL[iL + 1];
        int c = 0;
        int e = p0;
        while (e < p1) {
            int n = p1 - e; n = n > 8 ? 8 : n;
            int b8[8];
#pragma unroll
            for (int j = 0; j < 8; j++) b8[j] = csrL[e + (j < n ? j : 0)];
            unsigned short n8[8];
#pragma unroll
            for (int j = 0; j < 8; j++) n8[j] = newLs[b8[j]];
#pragma unroll
            for (int j = 0; j < 8; j++)
                if (j < n && n8[j] != 0xFFFFu && c < FCAP) fadjL[p * FCAP + c++] = n8[j];
            e += n;
        }
        fcntL[p] = c;
    }
    __syncthreads();

    // ---- Phase F: GAT features, wave-uniform head -> scalar Wg/a loads
    for (int rnd = 0; rnd < 2; rnd++) {
        int task = rnd == 0 ? tid : 1024 + tid;
        bool on = rnd == 0 || tid < KPAD;
        if (on) {
            int hh = __builtin_amdgcn_readfirstlane(task >> 9);   // wave-uniform head
            int p = task & (KPAD - 1);
            if (p < KSEL) {
                float xi[10];
#pragma unroll
                for (int k = 0; k < 10; k++) xi[k] = xpL[p * 10 + k];
                float v[NC];
                float as_ = 0.f, ad_ = 0.f;
#pragma unroll
                for (int c = 0; c < NC; c++) {
                    int j = hh * NC + c;
                    float vv = 0.f;
#pragma unroll
                    for (int k = 0; k < 10; k++) vv += xi[k] * Wg[k * HC + j];
                    v[c] = vv;
                    as_ += vv * a_srcw[j];
                    ad_ += vv * a_dstw[j];
                }
                float4* hr = (float4*)(hfL + p * HC + hh * NC);
#pragma unroll
                for (int q = 0; q < 5; q++)
                    hr[q] = make_float4(v[4 * q], v[4 * q + 1], v[4 * q + 2], v[4 * q + 3]);
                alsL[p * NH + hh] = as_;
                aldL[p * NH + hh] = ad_;
            }
        }
    }
    __syncthreads();

    // ---- Phase G: online single-pass softmax agg + butterfly-lite readout
    {
        float res[NC];
#pragma unroll
        for (int rnd = 0; rnd < 2; rnd++) {
            int task = rnd == 0 ? tid : 1024 + tid;
            bool on = rnd == 0 || tid < KPAD;
            int hh = task >> 9, p = task & (KPAD - 1);
            if (on) {
                if (p < KSEL) {
                    float aldp = aldL[p * NH + hh];
                    float lself = leaky(alsL[p * NH + hh] + aldp);
                    int c = fcntL[p];
                    const float4* hp = (const float4*)(hfL + p * HC + hh * NC);
                    float4 r0 = hp[0], r1 = hp[1], r2 = hp[2], r3 = hp[3], r4 = hp[4];
                    float wsum = 1.f;   // self weight exp(lself-lself)=1
                    for (int e = 0; e < c; e++) {
                        int idx = fadjL[p * FCAP + e];
                        float w = __expf(leaky(alsL[idx * NH + hh] + aldp) - lself);
                        wsum += w;
                        const float4* hq = (const float4*)(hfL + idx * HC + hh * NC);
                        float4 t0 = hq[0], t1 = hq[1], t2 = hq[2], t3 = hq[3], t4 = hq[4];
                        r0.x += w * t0.x; r0.y += w * t0.y; r0.z += w * t0.z; r0.w += w * t0.w;
                        r1.x += w * t1.x; r1.y += w * t1.y; r1.z += w * t1.z; r1.w += w * t1.w;
                        r2.x += w * t2.x; r2.y += w * t2.y; r2.z += w * t2.z; r2.w += w * t2.w;
                        r3.x += w * t3.x; r3.y += w * t3.y; r3.z += w * t3.z; r3.w += w * t3.w;
                        r4.x += w * t4.x; r4.y += w * t4.y; r4.z += w * t4.z; r4.w += w * t4.w;
                    }
                    float inv = 1.f / wsum;
                    res[0] = r0.x * inv;  res[1] = r0.y * inv;  res[2] = r0.z * inv;  res[3] = r0.w * inv;
                    res[4] = r1.x * inv;  res[5] = r1.y * inv;  res[6] = r1.z * inv;  res[7] = r1.w * inv;
                    res[8] = r2.x * inv;  res[9] = r2.y * inv;  res[10] = r2.z * inv; res[11] = r2.w * inv;
                    res[12] = r3.x * inv; res[13] = r3.y * inv; res[14] = r3.z * inv; res[15] = r3.w * inv;
                    res[16] = r4.x * inv; res[17] = r4.y * inv; res[18] = r4.z * inv; res[19] = r4.w * inv;
                } else {
#pragma unroll
                    for (int cc = 0; cc < NC; cc++) res[cc] = 0.f;
                }
                // sum within aligned 8-lane group (p is lane-consecutive)
#pragma unroll
                for (int cc = 0; cc < NC; cc++) {
                    float v = res[cc];
                    v += __shfl_xor(v, 1, 64);
                    v += __shfl_xor(v, 2, 64);
                    v += __shfl_xor(v, 4, 64);
                    res[cc] = v;
                }
                if ((tid & 7) == 0) {
                    int slot = hh * 64 + (p >> 3);      // 0..191
                    float* gp = wred2 + slot * NC;
#pragma unroll
                    for (int cc = 0; cc < NC; cc++) gp[cc] = res[cc];
                }
            }
        }
    }
    __syncthreads();
    if (tid < HC) {
        int hh = tid / NC, c = tid - hh * NC;
        float a = 0.f;
        for (int w = 0; w < 64; w++) a += wred2[(hh * 64 + w) * NC + c];
        goutL[tid] = a + (float)KSEL * bg[tid];
    }
    __syncthreads();

    // ---- Phase H: MLP + log_softmax
    if (tid < 30) {
        float s = bf1[tid];
#pragma unroll
        for (int k = 0; k < HC; k++) s += goutL[k] * Wf1[k * 30 + tid];
        hidL[tid] = s > 0.f ? s : 0.f;
    }
    __syncthreads();
    if (tid == 0) {
        float z[3];
#pragma unroll
        for (int j = 0; j < 3; j++) {
            float s = bf2[j];
            for (int k = 0; k < 30; k++) s += hidL[k] * Wf2[k * 3 + j];
            z[j] = s;
        }
        float m = fmaxf(z[0], fmaxf(z[1], z[2]));
        float lse = logf(expf(z[0] - m) + expf(z[1] - m) + expf(z[2] - m)) + m;
#pragma unroll
        for (int j = 0; j < 3; j++) out[g * 3 + j] = z[j] - lse;
    }
}

extern "C" void kernel_launch(void* const* d_in, const int* in_sizes, int n_in,
                              void* d_out, int out_size, void* d_ws, size_t ws_size,
                              hipStream_t stream) {
    const float* x     = (const float*)d_in[0];
    const int*   src   = (const int*)d_in[1];
    const int*   dst   = (const int*)d_in[2];
    const float* W1    = (const float*)d_in[4];
    const float* b1    = (const float*)d_in[5];
    const float* Ws    = (const float*)d_in[6];
    const float* bs    = (const float*)d_in[7];
    const float* Wg    = (const float*)d_in[8];
    const float* a_src = (const float*)d_in[9];
    const float* a_dst = (const float*)d_in[10];
    const float* bg    = (const float*)d_in[11];
    const float* Wf1   = (const float*)d_in[12];
    const float* bf1   = (const float*)d_in[13];
    const float* Wf2   = (const float*)d_in[14];
    const float* bf2   = (const float*)d_in[15];
    float* out = (float*)d_out;
    (void)d_ws; (void)ws_size;   // no workspace: avoids the 41 us harness re-poison fill

    k_all<<<G, 1024, 0, stream>>>(x, src, dst, W1, b1, Ws, bs, Wg, a_src, a_dst,
                                  bg, Wf1, bf1, Wf2, bf2, out);
}

// Round 12
// 118.864 us; speedup vs baseline: 1.3089x; 1.0857x over previous
//
#include <hip/hip_runtime.h>
#include <math.h>

#define G    64
#define NPG  2048
#define NTOT (G * NPG)          // 131072
#define EPG  (NPG * 8)          // 16384 edges per graph
#define KSEL 410
#define NH   3
#define NC   20
#define HC   60
#define FCAP 24
#define KPAD 512
#define RP   12                 // row: x/x1[0..9], dinv@10, hs@11 (48 B); dinv dup @5 in A..B

// ---- LDS arena (bytes). Phases: A csr+stage-x, B gcn10(linearity, in-place x1),
//      C scorer, D topk, E xp+fadj, F gat feat, G agg+readout, H mlp.
// hist region triple-duty: degree hist/cursors [A], pr=dinv*hs [B..C], radix bins [D].
// wred2 (group partials) overlays xp, which dies after F.
#define OFF_H1P   0             // 98304  rows 2048x12f           [A..E]
#define OFF_XP    0             // 16400  xp 410x10f              [E..F]   (row head dead)
#define OFF_WRED2 0             // 15360  wred2 192x20f           [G]      (xp dead)
#define OFF_FADJ  16400         // 19680  fadj 410x24 u16         [E..G]
#define OFF_FCNT  36080         // 1648   fcnt int                [E..G]
#define OFF_HF    37728         // 98400  hf 410x60f              [F..G]
#define OFF_CSR   98304         // 32768  csr u16                 [A..E]
#define OFF_HIST  131072        // 8192   hist[A] / pr[B..C] / bins[D]
#define OFF_RS    139264        // 8192   rs int                  [A..E]
#define OFF_ALS   139264        // 4920   als                     [F..G]   (rs dead)
#define OFF_ALD   144184        // 4920   ald                     [F..G]
#define OFF_SK    147456        // 8192   sk u32                  [C..E]
#define OFF_GOUT  151024        // 240    [G..H]                  (sk dead)
#define OFF_HID   151264        // 120    [H]
#define OFF_NEWL  155648        // 4096   newL u16                [C..E]
#define OFF_PERML 159744        // 824    permL u16               [D..E]
#define OFF_WSUM  160568        // 64
#define OFF_FLAGS 160632        // 16
#define ARENA_SZ  160648

__device__ inline float leaky(float x) { return x >= 0.f ? x : 0.2f * x; }

__device__ inline int wave_incl_scan(int v) {
    int lane = threadIdx.x & 63;
#pragma unroll
    for (int d = 1; d < 64; d <<= 1) {
        int t = __shfl_up(v, d, 64);
        if (lane >= d) v += t;
    }
    return v;
}

// 8-lane group sum on the VALU pipe (DPP), zero DS-pipe ops.
// quad_perm xor1 (0xB1), quad_perm xor2 (0x4E), row_half_mirror (0x141):
// after the two quad steps each quad is uniform, so l^7 delivers l^4's value.
__device__ inline float dpp_sum8(float v) {
    int t;
    t = __builtin_amdgcn_update_dpp(0, __float_as_int(v), 0xB1, 0xF, 0xF, true);
    v += __int_as_float(t);
    t = __builtin_amdgcn_update_dpp(0, __float_as_int(v), 0x4E, 0xF, 0xF, true);
    v += __int_as_float(t);
    t = __builtin_amdgcn_update_dpp(0, __float_as_int(v), 0x141, 0xF, 0xF, true);
    v += __int_as_float(t);
    return v;
}

__global__ __launch_bounds__(1024, 4) void k_all(
    const float* __restrict__ x, const int* __restrict__ src, const int* __restrict__ dst,
    const float* __restrict__ W1, const float* __restrict__ b1,
    const float* __restrict__ Ws, const float* __restrict__ bs,
    const float* __restrict__ Wg, const float* __restrict__ a_srcw,
    const float* __restrict__ a_dstw, const float* __restrict__ bg,
    const float* __restrict__ Wf1, const float* __restrict__ bf1,
    const float* __restrict__ Wf2, const float* __restrict__ bf2,
    float* __restrict__ out)
{
    __shared__ __align__(16) char arena[ARENA_SZ];
    float*          h1p   = (float*)(arena + OFF_H1P);
    float*          xpL   = (float*)(arena + OFF_XP);
    float*          wred2 = (float*)(arena + OFF_WRED2);
    unsigned short* fadjL = (unsigned short*)(arena + OFF_FADJ);
    int*            fcntL = (int*)(arena + OFF_FCNT);
    float*          hfL   = (float*)(arena + OFF_HF);
    unsigned short* csrL  = (unsigned short*)(arena + OFF_CSR);
    int*            hist  = (int*)(arena + OFF_HIST);
    float*          prB   = (float*)(arena + OFF_HIST);   // aliases hist [B..C]
    int*            rsL   = (int*)(arena + OFF_RS);
    float*          alsL  = (float*)(arena + OFF_ALS);
    float*          aldL  = (float*)(arena + OFF_ALD);
    unsigned*       skL   = (unsigned*)(arena + OFF_SK);
    float*          goutL = (float*)(arena + OFF_GOUT);
    float*          hidL  = (float*)(arena + OFF_HID);
    unsigned short* newLs = (unsigned short*)(arena + OFF_NEWL);
    unsigned short* permL = (unsigned short*)(arena + OFF_PERML);
    int*            wsumL = (int*)(arena + OFF_WSUM);
    int*            flags = (int*)(arena + OFF_FLAGS);
#define bselS  flags[0]
#define bneedS flags[1]

    int g = blockIdx.x, tid = threadIdx.x, wid = tid >> 6;
    int nbase = g * NPG, ebase = g * EPG;
    const int4* dst4 = (const int4*)(dst + ebase);
    const int4* src4 = (const int4*)(src + ebase);

    // ---- Phase A: zero hist; stage RAW x rows (GCN linearity defers W1)
    for (int i = tid; i < NPG; i += 1024) hist[i] = 0;
    for (int i = tid; i < NPG; i += 1024) {
        const float* xr = x + (size_t)(nbase + i) * 5;
        float x0 = xr[0], x1v = xr[1], x2 = xr[2], x3 = xr[3], x4 = xr[4];
        float4* row = (float4*)(h1p + i * RP);
        row[0] = make_float4(x0, x1v, x2, x3);
        row[1] = make_float4(x4, 0.f, 0.f, 0.f);   // slot5 = dinv (written in scan)
    }
    __syncthreads();
    for (int e4 = tid; e4 < EPG / 4; e4 += 1024) {   // int4-vectorized degree count
        int4 d = dst4[e4];
        atomicAdd(&hist[d.x - nbase], 1);
        atomicAdd(&hist[d.y - nbase], 1);
        atomicAdd(&hist[d.z - nbase], 1);
        atomicAdd(&hist[d.w - nbase], 1);
    }
    __syncthreads();
    {   // exclusive scan, redundant-prefix; dinv -> slots 5 (gather) and 10 (C/E)
        int b2 = tid * 2;
        int v0 = hist[b2], v1 = hist[b2 + 1];
        int s = v0 + v1;
        int incl = wave_incl_scan(s);
        if ((tid & 63) == 63) wsumL[wid] = incl;
        __syncthreads();
        int pre = 0;
#pragma unroll
        for (int w = 0; w < 16; w++) { int t = wsumL[w]; if (w < wid) pre += t; }
        int base = pre + incl - s;
        rsL[b2] = base;
        rsL[b2 + 1] = base + v0;
        float di0 = rsqrtf((float)v0 + 1.0f);
        float di1 = rsqrtf((float)v1 + 1.0f);
        h1p[b2 * RP + 5]        = di0;
        h1p[b2 * RP + 10]       = di0;
        h1p[(b2 + 1) * RP + 5]  = di1;
        h1p[(b2 + 1) * RP + 10] = di1;
        hist[b2] = 0; hist[b2 + 1] = 0;              // cursors
    }
    __syncthreads();
    for (int e4 = tid; e4 < EPG / 4; e4 += 1024) {   // int4-vectorized CSR fill
        int4 s4 = src4[e4];
        int4 d4 = dst4[e4];
        int dl, pos;
        dl = d4.x - nbase; pos = rsL[dl] + atomicAdd(&hist[dl], 1); csrL[pos] = (unsigned short)(s4.x - nbase);
        dl = d4.y - nbase; pos = rsL[dl] + atomicAdd(&hist[dl], 1); csrL[pos] = (unsigned short)(s4.y - nbase);
        dl = d4.z - nbase; pos = rsL[dl] + atomicAdd(&hist[dl], 1); csrL[pos] = (unsigned short)(s4.z - nbase);
        dl = d4.w - nbase; pos = rsL[dl] + atomicAdd(&hist[dl], 1); csrL[pos] = (unsigned short)(s4.w - nbase);
    }
    __syncthreads();

    // ---- Phase B: 5-wide x gather via linearity; W1 once/node; x1 in place; pr -> hist
    {
        int i0 = tid, i1 = tid + 1024;
        int e0 = rsL[i0], e0e = rsL[i0 + 1];
        int e1 = rsL[i1], e1e = (i1 == NPG - 1) ? EPG : rsL[i1 + 1];
        float a0[5], a1[5];
#pragma unroll
        for (int j = 0; j < 5; j++) { a0[j] = 0.f; a1[j] = 0.f; }
        while (e0 < e0e || e1 < e1e) {
            if (e0 < e0e) {
                int s = csrL[e0++];
                float4 r0 = *(const float4*)(h1p + s * RP);
                float2 r1 = *(const float2*)(h1p + s * RP + 4);   // x4, dinv
                float dv = r1.y;
                a0[0] += r0.x * dv; a0[1] += r0.y * dv; a0[2] += r0.z * dv;
                a0[3] += r0.w * dv; a0[4] += r1.x * dv;
            }
            if (e1 < e1e) {
                int s = csrL[e1++];
                float4 r0 = *(const float4*)(h1p + s * RP);
                float2 r1 = *(const float2*)(h1p + s * RP + 4);
                float dv = r1.y;
                a1[0] += r0.x * dv; a1[1] += r0.y * dv; a1[2] += r0.z * dv;
                a1[3] += r0.w * dv; a1[4] += r1.x * dv;
            }
        }
        float4 s0 = *(const float4*)(h1p + i0 * RP);
        float2 s0b = *(const float2*)(h1p + i0 * RP + 4);
        float4 s1 = *(const float4*)(h1p + i1 * RP);
        float2 s1b = *(const float2*)(h1p + i1 * RP + 4);
        float di0 = s0b.y, d20 = di0 * di0;
        float di1 = s1b.y, d21 = di1 * di1;
        float y0[5], y1[5];
        y0[0] = a0[0] * di0 + s0.x * d20;
        y0[1] = a0[1] * di0 + s0.y * d20;
        y0[2] = a0[2] * di0 + s0.z * d20;
        y0[3] = a0[3] * di0 + s0.w * d20;
        y0[4] = a0[4] * di0 + s0b.x * d20;
        y1[0] = a1[0] * di1 + s1.x * d21;
        y1[1] = a1[1] * di1 + s1.y * d21;
        y1[2] = a1[2] * di1 + s1.z * d21;
        y1[3] = a1[3] * di1 + s1.w * d21;
        y1[4] = a1[4] * di1 + s1b.x * d21;
        float v0[10], v1[10];
#pragma unroll
        for (int k = 0; k < 10; k++) {
            float b = b1[k];
            float c0 = b, c1 = b;
#pragma unroll
            for (int j = 0; j < 5; j++) {
                float w = W1[j * 10 + k];
                c0 += y0[j] * w;
                c1 += y1[j] * w;
            }
            v0[k] = c0; v1[k] = c1;
        }
        float hs0 = 0.f, hs1 = 0.f;
#pragma unroll
        for (int k = 0; k < 10; k++) { float w = Ws[k]; hs0 += v0[k] * w; hs1 += v1[k] * w; }
        __syncthreads();   // all gathers complete before any in-place overwrite
        float4* w0 = (float4*)(h1p + i0 * RP);
        w0[0] = make_float4(v0[0], v0[1], v0[2], v0[3]);
        w0[1] = make_float4(v0[4], v0[5], v0[6], v0[7]);
        w0[2] = make_float4(v0[8], v0[9], di0, hs0);
        float4* w1 = (float4*)(h1p + i1 * RP);
        w1[0] = make_float4(v1[0], v1[1], v1[2], v1[3]);
        w1[1] = make_float4(v1[4], v1[5], v1[6], v1[7]);
        w1[2] = make_float4(v1[8], v1[9], di1, hs1);
        prB[i0] = hs0 * di0;
        prB[i1] = hs1 * di1;
    }
    __syncthreads();

    // ---- Phase C: scorer gather; keys kept in REGISTERS for D's histogram passes
    unsigned kr0, kr1;
    {
        float bsv = bs[0];
        int i0 = tid, i1 = tid + 1024;
        float2 own0 = *(const float2*)(h1p + i0 * RP + 10);   // dinv, hs
        float2 own1 = *(const float2*)(h1p + i1 * RP + 10);
        int e0 = rsL[i0], e0e = rsL[i0 + 1];
        int e1 = rsL[i1], e1e = (i1 == NPG - 1) ? EPG : rsL[i1 + 1];
        float a0 = 0.f, a1 = 0.f;
        while (e0 < e0e || e1 < e1e) {
            if (e0 < e0e) a0 += prB[csrL[e0++]];
            if (e1 < e1e) a1 += prB[csrL[e1++]];
        }
        float sc0 = own0.x * a0 + own0.y * own0.x * own0.x + bsv;
        float sc1 = own1.x * a1 + own1.y * own1.x * own1.x + bsv;
        unsigned u0 = __float_as_uint(sc0);
        unsigned u1 = __float_as_uint(sc1);
        kr0 = (u0 & 0x80000000u) ? ~u0 : (u0 | 0x80000000u);
        kr1 = (u1 & 0x80000000u) ? ~u1 : (u1 | 0x80000000u);
        skL[i0] = kr0;
        skL[i1] = kr1;
        newLs[i0] = 0xFFFFu; newLs[i1] = 0xFFFFu;
    }
    int need = KSEL;
    unsigned prefix = 0;
    __syncthreads();
    for (int i = tid; i < NPG; i += 1024) hist[i] = 0;   // radix bins (pr dead)
    __syncthreads();

    // ---- Phase D: 3-level radix select (register keys; redundant-prefix scans)
    for (int lv = 0; lv < 3; lv++) {
#pragma unroll
        for (int t = 0; t < 2; t++) {
            unsigned k = t == 0 ? kr0 : kr1;
            bool match; unsigned bb;
            if (lv == 0)      { match = true;                  bb = k >> 21; }
            else if (lv == 1) { match = ((k >> 21) == prefix); bb = (k >> 10) & 0x7FFu; }
            else              { match = ((k >> 10) == prefix); bb = k & 0x3FFu; }
            if (match) atomicAdd(&hist[bb], 1);
        }
        __syncthreads();
        int b2 = tid * 2;
        int v0 = hist[b2], v1 = hist[b2 + 1];
        hist[b2] = 0; hist[b2 + 1] = 0;
        int s = v0 + v1;
        int incl = wave_incl_scan(s);
        if ((tid & 63) == 63) wsumL[wid] = incl;
        __syncthreads();
        int pre = 0, tot = 0;
#pragma unroll
        for (int w = 0; w < 16; w++) { int t = wsumL[w]; if (w < wid) pre += t; tot += t; }
        int base = pre + incl - s;
        { int Sb = tot - base;        int Sb1 = Sb - v0; if (Sb >= need && Sb1 < need) { bselS = b2;     bneedS = need - Sb1; } }
        { int Sb = tot - (base + v0); int Sb1 = Sb - v1; if (Sb >= need && Sb1 < need) { bselS = b2 + 1; bneedS = need - Sb1; } }
        __syncthreads();
        if (lv == 0)      prefix = (unsigned)bselS;
        else if (lv == 1) prefix = (prefix << 11) | (unsigned)bselS;
        else              prefix = (prefix << 10) | (unsigned)bselS;
        need = bneedS;
    }
    unsigned T = prefix;              // exact K-th largest key; need = #ties to take
    int greaterCnt = KSEL - need;

    // ---- Perm/newL: ONE packed scan (greater hi16, ties lo16), redundant-prefix
    {
        int b2 = tid * 2;
        unsigned k0 = skL[b2], k1 = skL[b2 + 1];
        int gt0 = k0 > T ? 1 : 0, gt1 = k1 > T ? 1 : 0;
        int eq0 = k0 == T ? 1 : 0, eq1 = k1 == T ? 1 : 0;
        int pack = ((gt0 + gt1) << 16) | (eq0 + eq1);
        int incl = wave_incl_scan(pack);
        if ((tid & 63) == 63) wsumL[wid] = incl;
        __syncthreads();
        int pre = 0;
#pragma unroll
        for (int w = 0; w < 16; w++) { int t = wsumL[w]; if (w < wid) pre += t; }
        int base = pre + incl - pack;
        int gb = base >> 16, eb = base & 0xFFFF;
        if (gt0) { permL[gb] = (unsigned short)b2; newLs[b2] = (unsigned short)gb; }
        if (gt1) { int r = gb + gt0; permL[r] = (unsigned short)(b2 + 1); newLs[b2 + 1] = (unsigned short)r; }
        if (eq0 && eb < need) { int p = greaterCnt + eb; permL[p] = (unsigned short)b2; newLs[b2] = (unsigned short)p; }
        if (eq1) { int r = eb + eq0; if (r < need) { int p = greaterCnt + r; permL[p] = (unsigned short)(b2 + 1); newLs[b2 + 1] = (unsigned short)p; } }
    }
    __syncthreads();

    // ---- Phase E: x1-read to regs | barrier | xp-write + fadj build (fused, 2 barriers)
    {
        float4 rq0, rq1, rq2; float tt = 0.f;
        int iL = 0;
        bool havep = (tid < KSEL);
        if (havep) {
            iL = permL[tid];
            unsigned k = skL[iL];
            unsigned u = (k & 0x80000000u) ? (k & 0x7FFFFFFFu) : ~k;
            tt = tanhf(__uint_as_float(u));
            const float4* xr = (const float4*)(h1p + iL * RP);
            rq0 = xr[0]; rq1 = xr[1]; rq2 = xr[2];
        }
        __syncthreads();   // all x1/h1p reads complete before xp/fadj overlay writes
        if (havep) {
            float* xp = xpL + tid * 10;
            xp[0] = rq0.x * tt; xp[1] = rq0.y * tt; xp[2] = rq0.z * tt; xp[3] = rq0.w * tt;
            xp[4] = rq1.x * tt; xp[5] = rq1.y * tt; xp[6] = rq1.z * tt; xp[7] = rq1.w * tt;
            xp[8] = rq2.x * tt; xp[9] = rq2.y * tt;
            // fadj build (chunk-of-8 prefetch); reads csr/rs/newL — untouched by overlays
            int p0 = rsL[iL], p1 = (iL == NPG - 1) ? EPG : rsL[iL + 1];
            int c = 0;
            int e = p0;
            while (e < p1) {
                int n = p1 - e; n = n > 8 ? 8 : n;
                int b8[8];
#pragma unroll
                for (int j = 0; j < 8; j++) b8[j] = csrL[e + (j < n ? j : 0)];
                unsigned short n8[8];
#pragma unroll
                for (int j = 0; j < 8; j++) n8[j] = newLs[b8[j]];
#pragma unroll
                for (int j = 0; j < 8; j++)
                    if (j < n && n8[j] != 0xFFFFu && c < FCAP) fadjL[tid * FCAP + c++] = n8[j];
                e += n;
            }
            fcntL[tid] = c;
        }
    }
    __syncthreads();

    // ---- Phase F: GAT features, wave-uniform head -> scalar Wg/a loads
    for (int rnd = 0; rnd < 2; rnd++) {
        int task = rnd == 0 ? tid : 1024 + tid;
        bool on = rnd == 0 || tid < 448;      // round 1 covers p<448 (>=KSEL dead)
        if (on) {
            int hh = __builtin_amdgcn_readfirstlane(task >> 9);   // wave-uniform head
            int p = task & (KPAD - 1);
            if (p < KSEL) {
                float xi[10];
#pragma unroll
                for (int k = 0; k < 10; k++) xi[k] = xpL[p * 10 + k];
                float v[NC];
                float as_ = 0.f, ad_ = 0.f;
#pragma unroll
                for (int c = 0; c < NC; c++) {
                    int j = hh * NC + c;
                    float vv = 0.f;
#pragma unroll
                    for (int k = 0; k < 10; k++) vv += xi[k] * Wg[k * HC + j];
                    v[c] = vv;
                    as_ += vv * a_srcw[j];
                    ad_ += vv * a_dstw[j];
                }
                float4* hr = (float4*)(hfL + p * HC + hh * NC);
#pragma unroll
                for (int q = 0; q < 5; q++)
                    hr[q] = make_float4(v[4 * q], v[4 * q + 1], v[4 * q + 2], v[4 * q + 3]);
                alsL[p * NH + hh] = as_;
                aldL[p * NH + hh] = ad_;
            }
        }
    }
    __syncthreads();

    // ---- Phase G: online softmax agg + DPP 8-lane readout (zero DS-pipe shuffles)
    {
        float res[NC];
#pragma unroll
        for (int rnd = 0; rnd < 2; rnd++) {
            int task = rnd == 0 ? tid : 1024 + tid;
            bool on = rnd == 0 || tid < 448;
            int hh = task >> 9, p = task & (KPAD - 1);
            if (on) {
                if (p < KSEL) {
                    float aldp = aldL[p * NH + hh];
                    float lself = leaky(alsL[p * NH + hh] + aldp);
                    int c = fcntL[p];
                    const float4* hp = (const float4*)(hfL + p * HC + hh * NC);
                    float4 r0 = hp[0], r1 = hp[1], r2 = hp[2], r3 = hp[3], r4 = hp[4];
                    float wsum = 1.f;   // self weight exp(lself-lself)=1
                    for (int e = 0; e < c; e++) {
                        int idx = fadjL[p * FCAP + e];
                        float w = __expf(leaky(alsL[idx * NH + hh] + aldp) - lself);
                        wsum += w;
                        const float4* hq = (const float4*)(hfL + idx * HC + hh * NC);
                        float4 t0 = hq[0], t1 = hq[1], t2 = hq[2], t3 = hq[3], t4 = hq[4];
                        r0.x += w * t0.x; r0.y += w * t0.y; r0.z += w * t0.z; r0.w += w * t0.w;
                        r1.x += w * t1.x; r1.y += w * t1.y; r1.z += w * t1.z; r1.w += w * t1.w;
                        r2.x += w * t2.x; r2.y += w * t2.y; r2.z += w * t2.z; r2.w += w * t2.w;
                        r3.x += w * t3.x; r3.y += w * t3.y; r3.z += w * t3.z; r3.w += w * t3.w;
                        r4.x += w * t4.x; r4.y += w * t4.y; r4.z += w * t4.z; r4.w += w * t4.w;
                    }
                    float inv = 1.f / wsum;
                    res[0] = r0.x * inv;  res[1] = r0.y * inv;  res[2] = r0.z * inv;  res[3] = r0.w * inv;
                    res[4] = r1.x * inv;  res[5] = r1.y * inv;  res[6] = r1.z * inv;  res[7] = r1.w * inv;
                    res[8] = r2.x * inv;  res[9] = r2.y * inv;  res[10] = r2.z * inv; res[11] = r2.w * inv;
                    res[12] = r3.x * inv; res[13] = r3.y * inv; res[14] = r3.z * inv; res[15] = r3.w * inv;
                    res[16] = r4.x * inv; res[17] = r4.y * inv; res[18] = r4.z * inv; res[19] = r4.w * inv;
                } else {
#pragma unroll
                    for (int cc = 0; cc < NC; cc++) res[cc] = 0.f;
                }
                // sum within aligned 8-lane group via DPP (VALU pipe)
#pragma unroll
                for (int cc = 0; cc < NC; cc++) res[cc] = dpp_sum8(res[cc]);
                if ((tid & 7) == 0) {
                    int slot = hh * 64 + (p >> 3);      // 0..191
                    float* gp = wred2 + slot * NC;
#pragma unroll
                    for (int cc = 0; cc < NC; cc++) gp[cc] = res[cc];
                }
            }
        }
    }
    __syncthreads();
    if (tid < HC) {
        int hh = tid / NC, c = tid - hh * NC;
        float a = 0.f;
        for (int w = 0; w < 52; w++) a += wred2[(hh * 64 + w) * NC + c];   // groups 52+ are +0
        goutL[tid] = a + (float)KSEL * bg[tid];
    }
    __syncthreads();

    // ---- Phase H: MLP + log_softmax
    if (tid < 30) {
        float s = bf1[tid];
#pragma unroll
        for (int k = 0; k < HC; k++) s += goutL[k] * Wf1[k * 30 + tid];
        hidL[tid] = s > 0.f ? s : 0.f;
    }
    __syncthreads();
    if (tid == 0) {
        float z[3];
#pragma unroll
        for (int j = 0; j < 3; j++) {
            float s = bf2[j];
            for (int k = 0; k < 30; k++) s += hidL[k] * Wf2[k * 3 + j];
            z[j] = s;
        }
        float m = fmaxf(z[0], fmaxf(z[1], z[2]));
        float lse = logf(expf(z[0] - m) + expf(z[1] - m) + expf(z[2] - m)) + m;
#pragma unroll
        for (int j = 0; j < 3; j++) out[g * 3 + j] = z[j] - lse;
    }
}

extern "C" void kernel_launch(void* const* d_in, const int* in_sizes, int n_in,
                              void* d_out, int out_size, void* d_ws, size_t ws_size,
                              hipStream_t stream) {
    const float* x     = (const float*)d_in[0];
    const int*   src   = (const int*)d_in[1];
    const int*   dst   = (const int*)d_in[2];
    const float* W1    = (const float*)d_in[4];
    const float* b1    = (const float*)d_in[5];
    const float* Ws    = (const float*)d_in[6];
    const float* bs    = (const float*)d_in[7];
    const float* Wg    = (const float*)d_in[8];
    const float* a_src = (const float*)d_in[9];
    const float* a_dst = (const float*)d_in[10];
    const float* bg    = (const float*)d_in[11];
    const float* Wf1   = (const float*)d_in[12];
    const float* bf1   = (const float*)d_in[13];
    const float* Wf2   = (const float*)d_in[14];
    const float* bf2   = (const float*)d_in[15];
    float* out = (float*)d_out;
    (void)d_ws; (void)ws_size;   // no workspace: avoids the 41 us harness re-poison fill

    k_all<<<G, 1024, 0, stream>>>(x, src, dst, W1, b1, Ws, bs, Wg, a_src, a_dst,
                                  bg, Wf1, bf1, Wf2, bf2, out);
}